// Round 12
// baseline (279.665 us; speedup 1.0000x reference)
//
#include <hip/hip_runtime.h>
#include <cstdint>
#include <cstddef>

#define B_ 64
#define C_ 256
#define N_ 1024
#define LOG2E 1.4426950408889634f

typedef short v8s __attribute__((ext_vector_type(8)));
typedef float v4f __attribute__((ext_vector_type(4)));
typedef unsigned int u32;
typedef unsigned short u16;

#define VMCNT(N) asm volatile("s_waitcnt vmcnt(" #N ")" ::: "memory")
#define LGKM0 asm volatile("s_waitcnt lgkmcnt(0)" ::: "memory")
#define SBAR __builtin_amdgcn_s_barrier()
#define SCHEDB __builtin_amdgcn_sched_barrier(0)

__device__ __forceinline__ float bf2f(u16 u) {
  return __uint_as_float(((u32)u) << 16);
}
__device__ __forceinline__ u16 f2bf(float f) {
  u32 x = __float_as_uint(f);
  x += 0x7fffu + ((x >> 16) & 1u);
  return (u16)(x >> 16);
}
__device__ __forceinline__ u32 pack2(float a, float b) {
  return (u32)f2bf(a) | ((u32)f2bf(b) << 16);
}
__device__ __forceinline__ u32 cvtpk(float lo, float hi) {
  u32 r;
  asm("v_cvt_pk_bf16_f32 %0, %1, %2" : "=v"(r) : "v"(lo), "v"(hi));
  return r;
}

typedef __attribute__((address_space(3))) unsigned int lds_as_t;
typedef __attribute__((address_space(1))) const unsigned int glb_as_t;
__device__ __forceinline__ void ld_lds16(const u16* g, u16* l) {
  __builtin_amdgcn_global_load_lds((glb_as_t*)g, (lds_as_t*)l, 16, 0, 0);
}

// ---------------------------------------------------------------------------
// prep: BN folding, weight casts / concat / transposes. q pre-scaled by log2e
// ---------------------------------------------------------------------------
__global__ __launch_bounds__(256) void prep(
    const float* __restrict__ g1, const float* __restrict__ b1,
    const float* __restrict__ m1, const float* __restrict__ v1,
    const float* __restrict__ g2, const float* __restrict__ b2,
    const float* __restrict__ m2, const float* __restrict__ v2,
    const float* __restrict__ wq, const float* __restrict__ bq,
    const float* __restrict__ wk, const float* __restrict__ bk,
    const float* __restrict__ wv, const float* __restrict__ bv,
    const float* __restrict__ pw1, const float* __restrict__ pw2,
    const float* __restrict__ dw1, const float* __restrict__ dw2,
    float* __restrict__ scale1, float* __restrict__ shift1,
    float* __restrict__ scale2, float* __restrict__ shift2,
    float* __restrict__ dwT1, float* __restrict__ dwT2,
    u16* __restrict__ pw1b, u16* __restrict__ pw2b, u16* __restrict__ wcatb,
    float* __restrict__ bcat) {
  const int gt = blockIdx.x * 256 + threadIdx.x;  // 16384 threads
  if (gt < 256) {
    float s1 = g1[gt] * rsqrtf(v1[gt] + 1e-5f);
    scale1[gt] = s1;
    shift1[gt] = b1[gt] - m1[gt] * s1;
    float s2 = g2[gt] * rsqrtf(v2[gt] + 1e-5f);
    scale2[gt] = s2;
    shift2[gt] = b2[gt] - m2[gt] * s2;
  }
  if (gt < 320)
    bcat[gt] = (gt < 32) ? bq[gt] * LOG2E
                         : (gt < 64) ? bk[gt - 32] : bv[gt - 64];
  if (gt < 2304) {
    dwT1[(gt % 9) * 256 + gt / 9] = dw1[gt];
    dwT2[(gt % 9) * 256 + gt / 9] = dw2[gt];
  }
  for (int e = gt; e < 65536; e += 16384) {
    pw1b[e] = f2bf(pw1[e]);
    pw2b[e] = f2bf(pw2[e]);
  }
  for (int e = gt; e < 81920; e += 16384) {
    const int o = e >> 8;
    float w = (o < 32) ? wq[e] * LOG2E
                       : (o < 64) ? wk[e - 8192] : wv[e - 16384];
    wcatb[e] = f2bf(w);
  }
}

// ---------------------------------------------------------------------------
// transpose x: [B][C][N] f32 -> [B][N][C] bf16  (64x64 tiles)
// ---------------------------------------------------------------------------
__global__ __launch_bounds__(256) void transpose_x(const float* __restrict__ x,
                                                   u16* __restrict__ xt) {
  __shared__ float t[64][65];
  const int b = blockIdx.z, c0 = blockIdx.y * 64, n0 = blockIdx.x * 64;
  const float* xp = x + ((size_t)b * C_ + c0) * N_ + n0;
  const int tn = threadIdx.x & 63, tc = threadIdx.x >> 6;
#pragma unroll
  for (int i = 0; i < 16; ++i)
    t[tc + 4 * i][tn] = xp[(size_t)(tc + 4 * i) * N_ + tn];
  __syncthreads();
  u16* op = xt + ((size_t)b * N_ + n0) * C_ + c0;
  const int oc = threadIdx.x & 63, on = threadIdx.x >> 6;
#pragma unroll
  for (int i = 0; i < 16; ++i)
    op[(size_t)(on + 4 * i) * C_ + oc] = f2bf(t[oc][on + 4 * i]);
}

// ---------------------------------------------------------------------------
// depthwise 3x3 NHWC bf16: src [B][N][C] -> dst [B][N][C]
// ---------------------------------------------------------------------------
__global__ __launch_bounds__(256) void dw_nhwc(const u16* __restrict__ src,
                                               const float* __restrict__ wT,
                                               u16* __restrict__ dst) {
  __shared__ float wl[9][256];
  const int b = blockIdx.y;
  for (int e = threadIdx.x; e < 2304; e += 256) wl[e >> 8][e & 255] = wT[e];
  __syncthreads();
  const int pl = threadIdx.x >> 5, c0 = (threadIdx.x & 31) * 8;
  const int p = blockIdx.x * 8 + pl;
  const int h = p >> 5, wx = p & 31;
  const u16* sp = src + (size_t)b * N_ * C_;
  float acc[8] = {0.f, 0.f, 0.f, 0.f, 0.f, 0.f, 0.f, 0.f};
#pragma unroll
  for (int dh = -1; dh <= 1; ++dh) {
    const int hh = h + dh;
    if (hh < 0 || hh > 31) continue;
#pragma unroll
    for (int dx = -1; dx <= 1; ++dx) {
      const int ww = wx + dx;
      if (ww < 0 || ww > 31) continue;
      const int k = (dh + 1) * 3 + (dx + 1);
      const uint4 v = *(const uint4*)(sp + (size_t)(hh * 32 + ww) * C_ + c0);
      const u32 vv[4] = {v.x, v.y, v.z, v.w};
#pragma unroll
      for (int j = 0; j < 4; ++j) {
        acc[2 * j] += bf2f((u16)(vv[j] & 0xffffu)) * wl[k][c0 + 2 * j];
        acc[2 * j + 1] += bf2f((u16)(vv[j] >> 16)) * wl[k][c0 + 2 * j + 1];
      }
    }
  }
  uint4 o4;
  o4.x = pack2(acc[0], acc[1]);
  o4.y = pack2(acc[2], acc[3]);
  o4.z = pack2(acc[4], acc[5]);
  o4.w = pack2(acc[6], acc[7]);
  *(uint4*)(dst + ((size_t)b * N_ + p) * C_ + c0) = o4;
}

// ---------------------------------------------------------------------------
// MFMA GEMM v2: double-buffered global_load_lds staging, counted vmcnt,
// raw barriers (no vmcnt(0) drains in the K-loop).
//   Y[n][o] = epi( sum_c X[n][c] * W[o][c] ), K = 256, tiles 128x128
// EPI 0: BN+ReLU -> bf16 NHWC (pw1)
// EPI 1: BN + bf16-NHWC residual -> bf16 NHWC (pw2)
// EPI 2: fused qkv (operands swapped so D rows = n):
//        o<64 -> qk [n][64] via LDS bounce; 64<=o<320 -> v CHW via bounce
// ---------------------------------------------------------------------------
template <int EPI>
__global__ __launch_bounds__(256) void gemm(
    const u16* __restrict__ X, const u16* __restrict__ W,
    const float* __restrict__ scale, const float* __restrict__ shift,
    const u16* __restrict__ resid, u16* __restrict__ Y, u16* __restrict__ Y2) {
  __shared__ u16 smem[32768];  // 2 x 32KB staging bufs; epilogue reuses
  u16(*Ys)[136] = (u16(*)[136])smem;
  u16(*YsQ)[68] = (u16(*)[68])smem;

  const int tid = threadIdx.x;
  const int b = blockIdx.z;
  const int n0 = blockIdx.x * 128, o0 = blockIdx.y * 128;
  const int wid = tid >> 6, lane = tid & 63;
  const int wn = wid & 1, wo = wid >> 1;
  const int l15 = lane & 15, l4 = lane >> 4;
  const int lr = lane >> 3, lc = (lane & 7) * 8;

  v4f acc[4][4];
#pragma unroll
  for (int i = 0; i < 4; ++i)
#pragma unroll
    for (int j = 0; j < 4; ++j) acc[i][j] = v4f{0.f, 0.f, 0.f, 0.f};

  // stage K-chunk kidx into buffer bufsel (8 x ld_lds16 per wave).
  auto stage = [&](int kidx, int bufsel) {
    const int k0 = (kidx & 3) * 64;
    u16* Xd = smem + bufsel * 16384;
    u16* Wd = smem + bufsel * 16384 + 8192;
#pragma unroll
    for (int g = 0; g < 4; ++g) {
      const int base = wid * 32 + g * 8;
      ld_lds16(X + ((size_t)b * N_ + n0 + base + lr) * C_ + k0 + lc,
               Xd + base * 64);
      int wr = o0 + base + lr;
      if (EPI == 2 && wr > 319) wr = 319;
      ld_lds16(W + (size_t)wr * C_ + k0 + lc, Wd + base * 64);
    }
  };

  stage(0, 0);
  stage(1, 1);

#pragma unroll
  for (int k = 0; k < 4; ++k) {
    const int cur = k & 1;
    if (k < 3) {
      VMCNT(8);  // own stage(k) done; stage(k+1) still in flight
    } else {
      VMCNT(0);  // last tile: drain everything
    }
    SCHEDB;
    SBAR;  // all waves' stage(k) complete
    const u16(*Xs)[64] = (const u16(*)[64])(smem + cur * 16384);
    const u16(*Ws)[64] = (const u16(*)[64])(smem + cur * 16384 + 8192);
#pragma unroll
    for (int ks = 0; ks < 2; ++ks) {
      v8s af[4], bf4[4];
#pragma unroll
      for (int f = 0; f < 4; ++f) {
        if constexpr (EPI != 2) {
          af[f] = *(const v8s*)&Ws[wo * 64 + f * 16 + l15][ks * 32 + l4 * 8];
          bf4[f] = *(const v8s*)&Xs[wn * 64 + f * 16 + l15][ks * 32 + l4 * 8];
        } else {
          af[f] = *(const v8s*)&Xs[wn * 64 + f * 16 + l15][ks * 32 + l4 * 8];
          bf4[f] = *(const v8s*)&Ws[wo * 64 + f * 16 + l15][ks * 32 + l4 * 8];
        }
      }
#pragma unroll
      for (int i = 0; i < 4; ++i)
#pragma unroll
        for (int j = 0; j < 4; ++j)
          acc[i][j] = __builtin_amdgcn_mfma_f32_16x16x32_bf16(
              af[i], bf4[j], acc[i][j], 0, 0, 0);
    }
    LGKM0;  // my reads of buf[cur] retired
    SBAR;   // all waves done reading buf[cur]
    SCHEDB;
    if (k < 2) stage(k + 2, cur);
  }

  if constexpr (EPI != 2) {
    // D rows = o (l4*4+r), cols = n (l15). Pack to Ys[n][o], store rows.
#pragma unroll
    for (int i = 0; i < 4; ++i) {
      const int oL = wo * 64 + i * 16 + l4 * 4;
      const int o = o0 + oL;
      const float4 sc = *(const float4*)&scale[o];
      const float4 sh = *(const float4*)&shift[o];
#pragma unroll
      for (int j = 0; j < 4; ++j) {
        const int nL = wn * 64 + j * 16 + l15;
        float y0 = acc[i][j][0] * sc.x + sh.x;
        float y1 = acc[i][j][1] * sc.y + sh.y;
        float y2 = acc[i][j][2] * sc.z + sh.z;
        float y3 = acc[i][j][3] * sc.w + sh.w;
        if constexpr (EPI == 0) {
          y0 = fmaxf(y0, 0.f);
          y1 = fmaxf(y1, 0.f);
          y2 = fmaxf(y2, 0.f);
          y3 = fmaxf(y3, 0.f);
        } else {
          const uint2 rb =
              *(const uint2*)(resid + ((size_t)b * N_ + n0 + nL) * C_ + o);
          y0 += bf2f((u16)(rb.x & 0xffffu));
          y1 += bf2f((u16)(rb.x >> 16));
          y2 += bf2f((u16)(rb.y & 0xffffu));
          y3 += bf2f((u16)(rb.y >> 16));
        }
        uint2 st;
        st.x = pack2(y0, y1);
        st.y = pack2(y2, y3);
        *(uint2*)&Ys[nL][oL] = st;
      }
    }
    __syncthreads();
#pragma unroll
    for (int s = 0; s < 8; ++s) {
      const int nL = s * 16 + (tid >> 4);
      const int slot = tid & 15;
      const uint4 v = *(const uint4*)&Ys[nL][slot * 8];
      *(uint4*)&Y[((size_t)b * N_ + n0 + nL) * C_ + o0 + slot * 8] = v;
    }
  } else {
    // D rows = n (l4*4+r), cols = o (l15).
    float bj[4];
#pragma unroll
    for (int j = 0; j < 4; ++j) {
      int o = o0 + wo * 64 + j * 16 + l15;
      bj[j] = shift[o > 319 ? 319 : o];
    }
    if (o0 == 0 && wo == 0) {
#pragma unroll
      for (int i = 0; i < 4; ++i) {
        const int nL = wn * 64 + i * 16 + l4 * 4;
#pragma unroll
        for (int j = 0; j < 4; ++j) {
          const int oL = j * 16 + l15;
#pragma unroll
          for (int r = 0; r < 4; ++r)
            YsQ[nL + r][oL] = f2bf(acc[i][j][r] + bj[j]);
        }
      }
    } else {
#pragma unroll
      for (int i = 0; i < 4; ++i) {
        const int nL = wn * 64 + i * 16 + l4 * 4;
#pragma unroll
        for (int j = 0; j < 4; ++j) {
          const int oL = wo * 64 + j * 16 + l15;
          uint2 st;
          st.x = pack2(acc[i][j][0] + bj[j], acc[i][j][1] + bj[j]);
          st.y = pack2(acc[i][j][2] + bj[j], acc[i][j][3] + bj[j]);
          *(uint2*)&Ys[oL][nL] = st;
        }
      }
    }
    __syncthreads();
    if (o0 == 0) {
#pragma unroll
      for (int s = 0; s < 4; ++s) {
        const int e = s * 256 + tid;
        const int row = e >> 3, seg = e & 7;
        const uint4 v = *(const uint4*)&YsQ[row][seg * 8];
        *(uint4*)&Y[((size_t)b * N_ + n0 + row) * 64 + seg * 8] = v;
      }
#pragma unroll
      for (int s = 0; s < 4; ++s) {
        const int e = s * 256 + tid;
        const int oL = 64 + (e >> 4), slot = e & 15;
        const uint4 v = *(const uint4*)&Ys[oL][slot * 8];
        *(uint4*)&Y2[((size_t)b * C_ + oL - 64) * N_ + n0 + slot * 8] = v;
      }
    } else {
#pragma unroll
      for (int s = 0; s < 8; ++s) {
        const int oL = s * 16 + (tid >> 4);
        const int c = o0 + oL - 64;
        if (c < 256) {
          const int slot = tid & 15;
          const uint4 v = *(const uint4*)&Ys[oL][slot * 8];
          *(uint4*)&Y2[((size_t)b * C_ + c) * N_ + n0 + slot * 8] = v;
        }
      }
    }
  }
}

// ---------------------------------------------------------------------------
// attn_stats: Madj[b][m] = rowmax + log2(rowsum) via lane-local online
// softmax. Zero LDS, zero barriers, zero per-tile cross-lane ops -> high
// occupancy, VALU-bound. qk [B][N][64] bf16 (q log2e-prescaled).
// Grid (b, m/64); 4 independent waves per block (16 m rows each).
// ---------------------------------------------------------------------------
__global__ __launch_bounds__(256) void attn_stats(const u16* __restrict__ qk,
                                                  float* __restrict__ madj) {
  const int b = blockIdx.x;
  const int m0 = blockIdx.y * 64;
  const int tid = threadIdx.x, wid = tid >> 6, lane = tid & 63;
  const int l15 = lane & 15, l4 = lane >> 4;
  const int mw = m0 + wid * 16;
  const u16* qkb = qk + (size_t)b * N_ * 64;
  const v8s qf = *(const v8s*)&qkb[(size_t)(mw + l15) * 64 + l4 * 8];

  float M = -3e38f, S = 0.f;
  v8s kf[4];
#pragma unroll
  for (int f = 0; f < 4; ++f)
    kf[f] = *(const v8s*)&qkb[(size_t)(f * 16 + l15) * 64 + 32 + l4 * 8];
  for (int t = 0; t < 16; ++t) {
    v8s kn[4];
    if (t < 15) {
      const int n1 = (t + 1) * 64;
#pragma unroll
      for (int f = 0; f < 4; ++f)
        kn[f] =
            *(const v8s*)&qkb[(size_t)(n1 + f * 16 + l15) * 64 + 32 + l4 * 8];
    }
    v4f lt[4];
#pragma unroll
    for (int f = 0; f < 4; ++f)
      lt[f] = __builtin_amdgcn_mfma_f32_16x16x32_bf16(
          kf[f], qf, v4f{0.f, 0.f, 0.f, 0.f}, 0, 0, 0);
    // lane-local online update (all 16 values belong to m = mw + l15)
    float pmax = -3e38f;
#pragma unroll
    for (int f = 0; f < 4; ++f)
#pragma unroll
      for (int r = 0; r < 4; ++r) pmax = fmaxf(pmax, lt[f][r]);
    const float Mn = fmaxf(M, pmax);
    float sum = 0.f;
#pragma unroll
    for (int f = 0; f < 4; ++f) {
      const float p0 = exp2f(lt[f][0] - Mn);
      const float p1 = exp2f(lt[f][1] - Mn);
      const float p2 = exp2f(lt[f][2] - Mn);
      const float p3 = exp2f(lt[f][3] - Mn);
      sum += (p0 + p1) + (p2 + p3);
    }
    S = S * exp2f(M - Mn) + sum;
    M = Mn;
    if (t < 15) {
#pragma unroll
      for (int f = 0; f < 4; ++f) kf[f] = kn[f];
    }
  }
  // combine the 4 l4-groups (same m = l15 within each 16-lane group)
#pragma unroll
  for (int off = 16; off <= 32; off <<= 1) {
    const float Mo = __shfl_xor(M, off);
    const float So = __shfl_xor(S, off);
    const float Mn = fmaxf(M, Mo);
    S = S * exp2f(M - Mn) + So * exp2f(Mo - Mn);
    M = Mn;
  }
  if (l4 == 0) madj[(size_t)b * N_ + mw + l15] = M + __log2f(S);
}

// ---------------------------------------------------------------------------
// attn_pv: c-split flash PV. Grid (b, m/64, c-half). Per block: 4 waves,
// 64 m rows x 128 c. P = exp2(s - Madj) is pre-normalized (no S pass).
// Vs[128][64] single-buffer, wave-private 32-c quarters via gload_lds;
// Pl dbuf; 1 raw barrier/tile with counted vmcnt (R11-proven scheme).
// LDS ~34.8KB -> 4 blocks/CU (16 waves).
// ---------------------------------------------------------------------------
__global__ __launch_bounds__(256, 4) void attn_pv(
    const u16* __restrict__ qk, const u16* __restrict__ vchw,
    const u16* __restrict__ abf, const float* __restrict__ madj,
    const float* __restrict__ gamma_p, float* __restrict__ out) {
  const int b = blockIdx.x;
  const int m0 = blockIdx.y * 64;
  const int ch0 = blockIdx.z * 128;
  const int tid = threadIdx.x, wid = tid >> 6, lane = tid & 63;
  const int l15 = lane & 15, l4 = lane >> 4;
  const int mw = m0 + wid * 16;
  const int cqL = wid * 32;  // wave-private V quarter (local rows)

  __shared__ u16 Vs[128][64];    // linear rows (gload_lds dest), src-swizzled
  __shared__ u16 Pl[2][64][72];  // P [m][n], double-buffered, pad-72

  const u16* qkb = qk + (size_t)b * N_ * 64;
  const u16* vb = vchw + (size_t)b * C_ * N_ + (size_t)ch0 * N_;
  const v8s qf = *(const v8s*)&qkb[(size_t)(mw + l15) * 64 + l4 * 8];
  const float mdj = madj[(size_t)b * N_ + mw + l15];

  const int s_row = lane >> 3;               // 0..7
  const int s_j = (lane & 7) ^ (s_row & 7);  // pre-swizzled global slot

  // stage V tile 0 into own quarter (4 gloads)
#pragma unroll
  for (int g = 0; g < 4; ++g) {
    const int base = cqL + g * 8;
    ld_lds16(vb + (size_t)(base + s_row) * N_ + s_j * 8, &Vs[base][0]);
  }
  v4f acc[4][2];
#pragma unroll
  for (int mf = 0; mf < 4; ++mf)
#pragma unroll
    for (int j = 0; j < 2; ++j) acc[mf][j] = v4f{0.f, 0.f, 0.f, 0.f};
  v8s kf[4];
#pragma unroll
  for (int f = 0; f < 4; ++f)
    kf[f] = *(const v8s*)&qkb[(size_t)(f * 16 + l15) * 64 + 32 + l4 * 8];
  VMCNT(0);  // V(0) + kf(0) landed (V quarters are wave-private)

  for (int t = 0; t < 16; ++t) {
    const int tb = t & 1;
    // QK^T (m-split): lt[f][r] = S[n = t*64 + f*16 + l4*4+r][m = mw+l15]
    v4f lt[4];
#pragma unroll
    for (int f = 0; f < 4; ++f)
      lt[f] = __builtin_amdgcn_mfma_f32_16x16x32_bf16(
          kf[f], qf, v4f{0.f, 0.f, 0.f, 0.f}, 0, 0, 0);
    // normalized P = exp2(s - Madj) -> Pl[tb]
#pragma unroll
    for (int f = 0; f < 4; ++f) {
      const float p0 = exp2f(lt[f][0] - mdj);
      const float p1 = exp2f(lt[f][1] - mdj);
      const float p2 = exp2f(lt[f][2] - mdj);
      const float p3 = exp2f(lt[f][3] - mdj);
      uint2 pw;
      pw.x = cvtpk(p0, p1);
      pw.y = cvtpk(p2, p3);
      *(uint2*)&Pl[tb][wid * 16 + l15][f * 16 + l4 * 4] = pw;
    }
    // kf prefetch for t+1 (wrap keeps vmcnt counts uniform)
    SCHEDB;
    {
      const int n1 = ((t + 1) & 15) * 64;
#pragma unroll
      for (int f = 0; f < 4; ++f)
        kf[f] =
            *(const v8s*)&qkb[(size_t)(n1 + f * 16 + l15) * 64 + 32 + l4 * 8];
    }
    SCHEDB;
    LGKM0;  // P writes retired -> visible after barrier
    SBAR;
    VMCNT(4);  // own V(t) gloads (4, older) done; kf(t+1) (4, newest) fly on
    SCHEDB;
    // PV: acc[mf][j] += P[m-frag mf] x V[c = ch0 + cqL + j*16 + l15]
    __builtin_amdgcn_s_setprio(1);
#pragma unroll
    for (int ks = 0; ks < 2; ++ks) {
      v8s pa[4];
#pragma unroll
      for (int mf = 0; mf < 4; ++mf)
        pa[mf] = *(const v8s*)&Pl[tb][mf * 16 + l15][ks * 32 + l4 * 8];
#pragma unroll
      for (int j = 0; j < 2; ++j) {
        const int col = 8 * (((ks * 4) + l4) ^ (l15 & 7));
        const v8s vf = *(const v8s*)&Vs[cqL + j * 16 + l15][col];
#pragma unroll
        for (int mf = 0; mf < 4; ++mf)
          acc[mf][j] = __builtin_amdgcn_mfma_f32_16x16x32_bf16(
              pa[mf], vf, acc[mf][j], 0, 0, 0);
      }
    }
    __builtin_amdgcn_s_setprio(0);
    // issue V(t+1) stage into OWN rows (wrap; only this wave reads them)
    SCHEDB;
    {
      const int n1 = ((t + 1) & 15) * 64;
#pragma unroll
      for (int g = 0; g < 4; ++g) {
        const int base = cqL + g * 8;
        ld_lds16(vb + (size_t)(base + s_row) * N_ + n1 + s_j * 8, &Vs[base][0]);
      }
    }
    SCHEDB;
  }

  const float gma = gamma_p[0];
#pragma unroll
  for (int mf = 0; mf < 4; ++mf) {
    const int mb = m0 + mf * 16 + l4 * 4;
#pragma unroll
    for (int j = 0; j < 2; ++j) {
      const int c = ch0 + cqL + j * 16 + l15;
      float4 y;
      float* yp = (float*)&y;
#pragma unroll
      for (int r = 0; r < 4; ++r) {
        const float av = bf2f(abf[((size_t)b * N_ + mb + r) * C_ + c]);
        yp[r] = fmaxf(gma * acc[mf][j][r] + av, 0.f);
      }
      *(float4*)&out[((size_t)b * C_ + c) * N_ + mb] = y;
    }
  }
}

// ---------------------------------------------------------------------------
extern "C" void kernel_launch(void* const* d_in, const int* in_sizes, int n_in,
                              void* d_out, int out_size, void* d_ws,
                              size_t ws_size, hipStream_t stream) {
  const float* x = (const float*)d_in[0];
  const float* dw1 = (const float*)d_in[1];
  const float* pw1 = (const float*)d_in[2];
  const float* bn1g = (const float*)d_in[3];
  const float* bn1b = (const float*)d_in[4];
  const float* bn1m = (const float*)d_in[5];
  const float* bn1v = (const float*)d_in[6];
  const float* dw2 = (const float*)d_in[7];
  const float* pw2 = (const float*)d_in[8];
  const float* bn2g = (const float*)d_in[9];
  const float* bn2b = (const float*)d_in[10];
  const float* bn2m = (const float*)d_in[11];
  const float* bn2v = (const float*)d_in[12];
  const float* wq = (const float*)d_in[13];
  const float* bq = (const float*)d_in[14];
  const float* wk = (const float*)d_in[15];
  const float* bk = (const float*)d_in[16];
  const float* wv = (const float*)d_in[17];
  const float* bv = (const float*)d_in[18];
  const float* gamma = (const float*)d_in[19];
  float* out = (float*)d_out;

  char* ws = (char*)d_ws;
  size_t off = 0;
  auto alloc = [&](size_t bytes) {
    void* p = ws + off;
    off += (bytes + 255) & ~(size_t)255;
    return p;
  };
  const size_t NE = (size_t)B_ * N_ * C_;  // 16.78M elements

  u16* bufA = (u16*)alloc(NE * 2);  // xt, later vchw
  u16* bufB = (u16*)alloc(NE * 2);  // t1, later t2
  u16* bufC = (u16*)alloc(NE * 2);  // y1, later qk
  u16* abf = (u16*)alloc(NE * 2);
  float* madj = (float*)alloc((size_t)B_ * N_ * 4);
  float* scale1 = (float*)alloc(256 * 4);
  float* shift1 = (float*)alloc(256 * 4);
  float* scale2 = (float*)alloc(256 * 4);
  float* shift2 = (float*)alloc(256 * 4);
  float* dwT1 = (float*)alloc(2304 * 4);
  float* dwT2 = (float*)alloc(2304 * 4);
  u16* pw1b = (u16*)alloc(65536 * 2);
  u16* pw2b = (u16*)alloc(65536 * 2);
  u16* wcatb = (u16*)alloc(81920 * 2);
  float* bcat = (float*)alloc(384 * 4);

  u16* xt = bufA;
  u16* t1 = bufB;
  u16* y1 = bufC;
  u16* t2 = bufB;
  u16* qkbuf = bufC;
  u16* vchw = bufA;

  prep<<<64, 256, 0, stream>>>(bn1g, bn1b, bn1m, bn1v, bn2g, bn2b, bn2m, bn2v,
                               wq, bq, wk, bk, wv, bv, pw1, pw2, dw1, dw2,
                               scale1, shift1, scale2, shift2, dwT1, dwT2,
                               pw1b, pw2b, wcatb, bcat);
  transpose_x<<<dim3(16, 4, B_), 256, 0, stream>>>(x, xt);
  dw_nhwc<<<dim3(128, B_), 256, 0, stream>>>(xt, dwT1, t1);
  gemm<0><<<dim3(8, 2, B_), 256, 0, stream>>>(t1, pw1b, scale1, shift1,
                                              nullptr, y1, nullptr);
  dw_nhwc<<<dim3(128, B_), 256, 0, stream>>>(y1, dwT2, t2);
  gemm<1><<<dim3(8, 2, B_), 256, 0, stream>>>(t2, pw2b, scale2, shift2, xt,
                                              abf, nullptr);
  gemm<2><<<dim3(8, 3, B_), 256, 0, stream>>>(abf, wcatb, nullptr, bcat,
                                              nullptr, qkbuf, vchw);
  attn_stats<<<dim3(64, 16), 256, 0, stream>>>(qkbuf, madj);
  attn_pv<<<dim3(64, 16, 2), 256, 0, stream>>>(qkbuf, vchw, abf, madj, gamma,
                                               out);
}

// Round 13
// 256.337 us; speedup vs baseline: 1.0910x; 1.0910x over previous
//
#include <hip/hip_runtime.h>
#include <cstdint>
#include <cstddef>

#define B_ 64
#define C_ 256
#define N_ 1024
#define LOG2E 1.4426950408889634f

typedef short v8s __attribute__((ext_vector_type(8)));
typedef float v4f __attribute__((ext_vector_type(4)));
typedef unsigned int u32;
typedef unsigned short u16;

#define VMCNT(N) asm volatile("s_waitcnt vmcnt(" #N ")" ::: "memory")
#define LGKM0 asm volatile("s_waitcnt lgkmcnt(0)" ::: "memory")
#define SBAR __builtin_amdgcn_s_barrier()
#define SCHEDB __builtin_amdgcn_sched_barrier(0)

__device__ __forceinline__ float bf2f(u16 u) {
  return __uint_as_float(((u32)u) << 16);
}
__device__ __forceinline__ u16 f2bf(float f) {
  u32 x = __float_as_uint(f);
  x += 0x7fffu + ((x >> 16) & 1u);
  return (u16)(x >> 16);
}
__device__ __forceinline__ u32 pack2(float a, float b) {
  return (u32)f2bf(a) | ((u32)f2bf(b) << 16);
}
__device__ __forceinline__ u32 cvtpk(float lo, float hi) {
  u32 r;
  asm("v_cvt_pk_bf16_f32 %0, %1, %2" : "=v"(r) : "v"(lo), "v"(hi));
  return r;
}

typedef __attribute__((address_space(3))) unsigned int lds_as_t;
typedef __attribute__((address_space(1))) const unsigned int glb_as_t;
__device__ __forceinline__ void ld_lds16(const u16* g, u16* l) {
  __builtin_amdgcn_global_load_lds((glb_as_t*)g, (lds_as_t*)l, 16, 0, 0);
}

// ---------------------------------------------------------------------------
// prep: BN folding, weight casts / concat / transposes. q pre-scaled by log2e
// ---------------------------------------------------------------------------
__global__ __launch_bounds__(256) void prep(
    const float* __restrict__ g1, const float* __restrict__ b1,
    const float* __restrict__ m1, const float* __restrict__ v1,
    const float* __restrict__ g2, const float* __restrict__ b2,
    const float* __restrict__ m2, const float* __restrict__ v2,
    const float* __restrict__ wq, const float* __restrict__ bq,
    const float* __restrict__ wk, const float* __restrict__ bk,
    const float* __restrict__ wv, const float* __restrict__ bv,
    const float* __restrict__ pw1, const float* __restrict__ pw2,
    const float* __restrict__ dw1, const float* __restrict__ dw2,
    float* __restrict__ scale1, float* __restrict__ shift1,
    float* __restrict__ scale2, float* __restrict__ shift2,
    float* __restrict__ dwT1, float* __restrict__ dwT2,
    u16* __restrict__ pw1b, u16* __restrict__ pw2b, u16* __restrict__ wcatb,
    float* __restrict__ bcat) {
  const int gt = blockIdx.x * 256 + threadIdx.x;  // 16384 threads
  if (gt < 256) {
    float s1 = g1[gt] * rsqrtf(v1[gt] + 1e-5f);
    scale1[gt] = s1;
    shift1[gt] = b1[gt] - m1[gt] * s1;
    float s2 = g2[gt] * rsqrtf(v2[gt] + 1e-5f);
    scale2[gt] = s2;
    shift2[gt] = b2[gt] - m2[gt] * s2;
  }
  if (gt < 320)
    bcat[gt] = (gt < 32) ? bq[gt] * LOG2E
                         : (gt < 64) ? bk[gt - 32] : bv[gt - 64];
  if (gt < 2304) {
    dwT1[(gt % 9) * 256 + gt / 9] = dw1[gt];
    dwT2[(gt % 9) * 256 + gt / 9] = dw2[gt];
  }
  for (int e = gt; e < 65536; e += 16384) {
    pw1b[e] = f2bf(pw1[e]);
    pw2b[e] = f2bf(pw2[e]);
  }
  for (int e = gt; e < 81920; e += 16384) {
    const int o = e >> 8;
    float w = (o < 32) ? wq[e] * LOG2E
                       : (o < 64) ? wk[e - 8192] : wv[e - 16384];
    wcatb[e] = f2bf(w);
  }
}

// ---------------------------------------------------------------------------
// transpose x: [B][C][N] f32 -> [B][N][C] bf16  (64x64 tiles)
// ---------------------------------------------------------------------------
__global__ __launch_bounds__(256) void transpose_x(const float* __restrict__ x,
                                                   u16* __restrict__ xt) {
  __shared__ float t[64][65];
  const int b = blockIdx.z, c0 = blockIdx.y * 64, n0 = blockIdx.x * 64;
  const float* xp = x + ((size_t)b * C_ + c0) * N_ + n0;
  const int tn = threadIdx.x & 63, tc = threadIdx.x >> 6;
#pragma unroll
  for (int i = 0; i < 16; ++i)
    t[tc + 4 * i][tn] = xp[(size_t)(tc + 4 * i) * N_ + tn];
  __syncthreads();
  u16* op = xt + ((size_t)b * N_ + n0) * C_ + c0;
  const int oc = threadIdx.x & 63, on = threadIdx.x >> 6;
#pragma unroll
  for (int i = 0; i < 16; ++i)
    op[(size_t)(on + 4 * i) * C_ + oc] = f2bf(t[oc][on + 4 * i]);
}

// ---------------------------------------------------------------------------
// depthwise 3x3 NHWC bf16: src [B][N][C] -> dst [B][N][C]
// ---------------------------------------------------------------------------
__global__ __launch_bounds__(256) void dw_nhwc(const u16* __restrict__ src,
                                               const float* __restrict__ wT,
                                               u16* __restrict__ dst) {
  __shared__ float wl[9][256];
  const int b = blockIdx.y;
  for (int e = threadIdx.x; e < 2304; e += 256) wl[e >> 8][e & 255] = wT[e];
  __syncthreads();
  const int pl = threadIdx.x >> 5, c0 = (threadIdx.x & 31) * 8;
  const int p = blockIdx.x * 8 + pl;
  const int h = p >> 5, wx = p & 31;
  const u16* sp = src + (size_t)b * N_ * C_;
  float acc[8] = {0.f, 0.f, 0.f, 0.f, 0.f, 0.f, 0.f, 0.f};
#pragma unroll
  for (int dh = -1; dh <= 1; ++dh) {
    const int hh = h + dh;
    if (hh < 0 || hh > 31) continue;
#pragma unroll
    for (int dx = -1; dx <= 1; ++dx) {
      const int ww = wx + dx;
      if (ww < 0 || ww > 31) continue;
      const int k = (dh + 1) * 3 + (dx + 1);
      const uint4 v = *(const uint4*)(sp + (size_t)(hh * 32 + ww) * C_ + c0);
      const u32 vv[4] = {v.x, v.y, v.z, v.w};
#pragma unroll
      for (int j = 0; j < 4; ++j) {
        acc[2 * j] += bf2f((u16)(vv[j] & 0xffffu)) * wl[k][c0 + 2 * j];
        acc[2 * j + 1] += bf2f((u16)(vv[j] >> 16)) * wl[k][c0 + 2 * j + 1];
      }
    }
  }
  uint4 o4;
  o4.x = pack2(acc[0], acc[1]);
  o4.y = pack2(acc[2], acc[3]);
  o4.z = pack2(acc[4], acc[5]);
  o4.w = pack2(acc[6], acc[7]);
  *(uint4*)(dst + ((size_t)b * N_ + p) * C_ + c0) = o4;
}

// ---------------------------------------------------------------------------
// MFMA GEMM v3: BK=32 double-buffered gload_lds staging + counted vmcnt +
// raw barriers. LDS = 34.8KB -> 4 blocks/CU (one round for the 1024 grid).
//   Y[n][o] = epi( sum_c X[n][c] * W[o][c] ), K = 256, tiles 128x128
// EPI 0: BN+ReLU -> bf16 NHWC (pw1)
// EPI 1: BN + bf16-NHWC residual -> bf16 NHWC (pw2)
// EPI 2: fused qkv (operands swapped so D rows = n):
//        o<64 -> qk [n][64] via LDS bounce; 64<=o<320 -> v CHW via bounce
// ---------------------------------------------------------------------------
template <int EPI>
__global__ __launch_bounds__(256, 4) void gemm(
    const u16* __restrict__ X, const u16* __restrict__ W,
    const float* __restrict__ scale, const float* __restrict__ shift,
    const u16* __restrict__ resid, u16* __restrict__ Y, u16* __restrict__ Y2) {
  __shared__ u16 smem[17408];  // 34.8KB: 2 x 16KB staging bufs; epi Ys 34KB
  u16(*Ys)[136] = (u16(*)[136])smem;
  u16(*YsQ)[68] = (u16(*)[68])smem;

  const int tid = threadIdx.x;
  const int b = blockIdx.z;
  const int n0 = blockIdx.x * 128, o0 = blockIdx.y * 128;
  const int wid = tid >> 6, lane = tid & 63;
  const int wn = wid & 1, wo = wid >> 1;
  const int l15 = lane & 15, l4 = lane >> 4;
  const int r16 = lane >> 2, c16 = (lane & 3) * 8;  // staging lane map

  v4f acc[4][4];
#pragma unroll
  for (int i = 0; i < 4; ++i)
#pragma unroll
    for (int j = 0; j < 4; ++j) acc[i][j] = v4f{0.f, 0.f, 0.f, 0.f};

  // stage K-chunk (32 wide) kidx into buffer bufsel: 4 x ld_lds16 per wave.
  // X [128][32] at buf+0, W [128][32] at buf+4096 (u16 units).
  auto stage = [&](int kidx, int bufsel) {
    const int k0 = (kidx & 7) * 32;
    u16* Xd = smem + bufsel * 8192;
    u16* Wd = Xd + 4096;
#pragma unroll
    for (int g = 0; g < 2; ++g) {
      const int base = wid * 32 + g * 16;
      ld_lds16(X + ((size_t)b * N_ + n0 + base + r16) * C_ + k0 + c16,
               Xd + base * 32);
      int wr = o0 + base + r16;
      if (EPI == 2 && wr > 319) wr = 319;
      ld_lds16(W + (size_t)wr * C_ + k0 + c16, Wd + base * 32);
    }
  };

  stage(0, 0);
  stage(1, 1);

#pragma unroll
  for (int k = 0; k < 8; ++k) {
    const int cur = k & 1;
    if (k < 7) {
      VMCNT(4);  // own stage(k) done; stage(k+1) still in flight
    } else {
      VMCNT(0);  // last chunk: drain everything
    }
    SCHEDB;
    SBAR;  // all waves' stage(k) complete
    const u16(*Xs)[32] = (const u16(*)[32])(smem + cur * 8192);
    const u16(*Ws)[32] = (const u16(*)[32])(smem + cur * 8192 + 4096);
    v8s af[4], bf4[4];
#pragma unroll
    for (int f = 0; f < 4; ++f) {
      if constexpr (EPI != 2) {
        af[f] = *(const v8s*)&Ws[wo * 64 + f * 16 + l15][l4 * 8];
        bf4[f] = *(const v8s*)&Xs[wn * 64 + f * 16 + l15][l4 * 8];
      } else {
        af[f] = *(const v8s*)&Xs[wn * 64 + f * 16 + l15][l4 * 8];
        bf4[f] = *(const v8s*)&Ws[wo * 64 + f * 16 + l15][l4 * 8];
      }
    }
#pragma unroll
    for (int i = 0; i < 4; ++i)
#pragma unroll
      for (int j = 0; j < 4; ++j)
        acc[i][j] = __builtin_amdgcn_mfma_f32_16x16x32_bf16(af[i], bf4[j],
                                                            acc[i][j], 0, 0, 0);
    LGKM0;  // my reads of buf[cur] retired
    SBAR;   // all waves done reading buf[cur]
    SCHEDB;
    if (k < 6) stage(k + 2, cur);
  }

  if constexpr (EPI != 2) {
    // D rows = o (l4*4+r), cols = n (l15). Pack to Ys[n][o], store rows.
#pragma unroll
    for (int i = 0; i < 4; ++i) {
      const int oL = wo * 64 + i * 16 + l4 * 4;
      const int o = o0 + oL;
      const float4 sc = *(const float4*)&scale[o];
      const float4 sh = *(const float4*)&shift[o];
#pragma unroll
      for (int j = 0; j < 4; ++j) {
        const int nL = wn * 64 + j * 16 + l15;
        float y0 = acc[i][j][0] * sc.x + sh.x;
        float y1 = acc[i][j][1] * sc.y + sh.y;
        float y2 = acc[i][j][2] * sc.z + sh.z;
        float y3 = acc[i][j][3] * sc.w + sh.w;
        if constexpr (EPI == 0) {
          y0 = fmaxf(y0, 0.f);
          y1 = fmaxf(y1, 0.f);
          y2 = fmaxf(y2, 0.f);
          y3 = fmaxf(y3, 0.f);
        } else {
          const uint2 rb =
              *(const uint2*)(resid + ((size_t)b * N_ + n0 + nL) * C_ + o);
          y0 += bf2f((u16)(rb.x & 0xffffu));
          y1 += bf2f((u16)(rb.x >> 16));
          y2 += bf2f((u16)(rb.y & 0xffffu));
          y3 += bf2f((u16)(rb.y >> 16));
        }
        uint2 st;
        st.x = pack2(y0, y1);
        st.y = pack2(y2, y3);
        *(uint2*)&Ys[nL][oL] = st;
      }
    }
    __syncthreads();
#pragma unroll
    for (int s = 0; s < 8; ++s) {
      const int nL = s * 16 + (tid >> 4);
      const int slot = tid & 15;
      const uint4 v = *(const uint4*)&Ys[nL][slot * 8];
      *(uint4*)&Y[((size_t)b * N_ + n0 + nL) * C_ + o0 + slot * 8] = v;
    }
  } else {
    // D rows = n (l4*4+r), cols = o (l15).
    float bj[4];
#pragma unroll
    for (int j = 0; j < 4; ++j) {
      int o = o0 + wo * 64 + j * 16 + l15;
      bj[j] = shift[o > 319 ? 319 : o];
    }
    if (o0 == 0 && wo == 0) {
#pragma unroll
      for (int i = 0; i < 4; ++i) {
        const int nL = wn * 64 + i * 16 + l4 * 4;
#pragma unroll
        for (int j = 0; j < 4; ++j) {
          const int oL = j * 16 + l15;
#pragma unroll
          for (int r = 0; r < 4; ++r)
            YsQ[nL + r][oL] = f2bf(acc[i][j][r] + bj[j]);
        }
      }
    } else {
#pragma unroll
      for (int i = 0; i < 4; ++i) {
        const int nL = wn * 64 + i * 16 + l4 * 4;
#pragma unroll
        for (int j = 0; j < 4; ++j) {
          const int oL = wo * 64 + j * 16 + l15;
          uint2 st;
          st.x = pack2(acc[i][j][0] + bj[j], acc[i][j][1] + bj[j]);
          st.y = pack2(acc[i][j][2] + bj[j], acc[i][j][3] + bj[j]);
          *(uint2*)&Ys[oL][nL] = st;
        }
      }
    }
    __syncthreads();
    if (o0 == 0) {
#pragma unroll
      for (int s = 0; s < 4; ++s) {
        const int e = s * 256 + tid;
        const int row = e >> 3, seg = e & 7;
        const uint4 v = *(const uint4*)&YsQ[row][seg * 8];
        *(uint4*)&Y[((size_t)b * N_ + n0 + row) * 64 + seg * 8] = v;
      }
#pragma unroll
      for (int s = 0; s < 4; ++s) {
        const int e = s * 256 + tid;
        const int oL = 64 + (e >> 4), slot = e & 15;
        const uint4 v = *(const uint4*)&Ys[oL][slot * 8];
        *(uint4*)&Y2[((size_t)b * C_ + oL - 64) * N_ + n0 + slot * 8] = v;
      }
    } else {
#pragma unroll
      for (int s = 0; s < 8; ++s) {
        const int oL = s * 16 + (tid >> 4);
        const int c = o0 + oL - 64;
        if (c < 256) {
          const int slot = tid & 15;
          const uint4 v = *(const uint4*)&Ys[oL][slot * 8];
          *(uint4*)&Y2[((size_t)b * C_ + c) * N_ + n0 + slot * 8] = v;
        }
      }
    }
  }
}

// ---------------------------------------------------------------------------
// flash (R11): c-split PV, wave-private V quarters, P double-buffer,
// counted-vmcnt raw-barrier sync (no vmcnt(0) drains in the main loop).
// ---------------------------------------------------------------------------
__global__ __launch_bounds__(256, 3) void flash(
    const u16* __restrict__ qk, const u16* __restrict__ vchw,
    const u16* __restrict__ abf, const float* __restrict__ gamma_p,
    float* __restrict__ out) {
  const int b = blockIdx.x;
  const int m0 = blockIdx.y * 64;
  const int tid = threadIdx.x, wid = tid >> 6, lane = tid & 63;
  const int l15 = lane & 15, l4 = lane >> 4;
  const int mw = m0 + wid * 16;
  const int cq = wid * 64;  // this wave's private c-quarter

  __shared__ u16 Vs[256][64];    // linear rows (gload_lds dest), src-swizzled
  __shared__ u16 Pl[2][64][72];  // P [m][n], double-buffered, pad-72
  __shared__ float Sl[64];

  const u16* qkb = qk + (size_t)b * N_ * 64;
  const u16* vb = vchw + (size_t)b * C_ * N_;
  const v8s qf = *(const v8s*)&qkb[(size_t)(mw + l15) * 64 + l4 * 8];

  const int s_row = lane >> 3;               // 0..7
  const int s_j = (lane & 7) ^ (s_row & 7);  // pre-swizzled global slot

  // stage V tile 0 into own quarter
#pragma unroll
  for (int g = 0; g < 8; ++g) {
    const int base = cq + g * 8;
    ld_lds16(vb + (size_t)(base + s_row) * N_ + s_j * 8, &Vs[base][0]);
  }

  // ---- pass 1: exact row max (m-split waves, n-blocks of 64) ----
  float Mloc = -3e38f;
  {
    v8s kf[4];
#pragma unroll
    for (int f = 0; f < 4; ++f)
      kf[f] = *(const v8s*)&qkb[(size_t)(f * 16 + l15) * 64 + 32 + l4 * 8];
    for (int t = 0; t < 16; ++t) {
      v8s kn[4];
      if (t < 15) {
        const int n1 = (t + 1) * 64;
#pragma unroll
        for (int f = 0; f < 4; ++f)
          kn[f] =
              *(const v8s*)&qkb[(size_t)(n1 + f * 16 + l15) * 64 + 32 + l4 * 8];
      }
#pragma unroll
      for (int f = 0; f < 4; ++f) {
        const v4f lt = __builtin_amdgcn_mfma_f32_16x16x32_bf16(
            kf[f], qf, v4f{0.f, 0.f, 0.f, 0.f}, 0, 0, 0);
        Mloc = fmaxf(Mloc, fmaxf(fmaxf(lt[0], lt[1]), fmaxf(lt[2], lt[3])));
      }
      if (t < 15) {
#pragma unroll
        for (int f = 0; f < 4; ++f) kf[f] = kn[f];
      }
    }
  }
  Mloc = fmaxf(Mloc, __shfl_xor(Mloc, 16));
  Mloc = fmaxf(Mloc, __shfl_xor(Mloc, 32));
  const float M = Mloc;

  // ---- pass 2 ----
  v4f acc[4][4];
#pragma unroll
  for (int mf = 0; mf < 4; ++mf)
#pragma unroll
    for (int j = 0; j < 4; ++j) acc[mf][j] = v4f{0.f, 0.f, 0.f, 0.f};
  float S0 = 0.f, S1 = 0.f, S2 = 0.f, S3 = 0.f;
  v8s kf[4];
#pragma unroll
  for (int f = 0; f < 4; ++f)
    kf[f] = *(const v8s*)&qkb[(size_t)(f * 16 + l15) * 64 + 32 + l4 * 8];
  VMCNT(0);  // own V(0) + kf(0) landed (per-wave; quarters are wave-private)

  for (int t = 0; t < 16; ++t) {
    const int tb = t & 1;
    v4f lt[4];
#pragma unroll
    for (int f = 0; f < 4; ++f)
      lt[f] = __builtin_amdgcn_mfma_f32_16x16x32_bf16(
          kf[f], qf, v4f{0.f, 0.f, 0.f, 0.f}, 0, 0, 0);
#pragma unroll
    for (int f = 0; f < 4; ++f) {
      const float p0 = exp2f(lt[f][0] - M);
      const float p1 = exp2f(lt[f][1] - M);
      const float p2 = exp2f(lt[f][2] - M);
      const float p3 = exp2f(lt[f][3] - M);
      S0 += p0;
      S1 += p1;
      S2 += p2;
      S3 += p3;
      uint2 pw;
      pw.x = cvtpk(p0, p1);
      pw.y = cvtpk(p2, p3);
      *(uint2*)&Pl[tb][wid * 16 + l15][f * 16 + l4 * 4] = pw;
    }
    SCHEDB;
    {
      const int n1 = ((t + 1) & 15) * 64;
#pragma unroll
      for (int f = 0; f < 4; ++f)
        kf[f] =
            *(const v8s*)&qkb[(size_t)(n1 + f * 16 + l15) * 64 + 32 + l4 * 8];
    }
    SCHEDB;
    LGKM0;  // P writes retired -> visible after barrier
    SBAR;
    VMCNT(4);  // own V(t) gloads (8, older) done; kf(t+1) (4, newest) fly on
    SCHEDB;
    __builtin_amdgcn_s_setprio(1);
#pragma unroll
    for (int ks = 0; ks < 2; ++ks) {
      v8s pa[4];
#pragma unroll
      for (int mf = 0; mf < 4; ++mf)
        pa[mf] = *(const v8s*)&Pl[tb][mf * 16 + l15][ks * 32 + l4 * 8];
#pragma unroll
      for (int j = 0; j < 4; ++j) {
        const int col = 8 * (((ks * 4) + l4) ^ (l15 & 7));
        const v8s vf = *(const v8s*)&Vs[cq + j * 16 + l15][col];
#pragma unroll
        for (int mf = 0; mf < 4; ++mf)
          acc[mf][j] = __builtin_amdgcn_mfma_f32_16x16x32_bf16(
              pa[mf], vf, acc[mf][j], 0, 0, 0);
      }
    }
    __builtin_amdgcn_s_setprio(0);
    SCHEDB;
    {
      const int n1 = ((t + 1) & 15) * 64;
#pragma unroll
      for (int g = 0; g < 8; ++g) {
        const int base = cq + g * 8;
        ld_lds16(vb + (size_t)(base + s_row) * N_ + n1 + s_j * 8, &Vs[base][0]);
      }
    }
    SCHEDB;
  }

  float S = (S0 + S1) + (S2 + S3);
  S += __shfl_xor(S, 16);
  S += __shfl_xor(S, 32);
  if (lane < 16) Sl[wid * 16 + lane] = 1.f / S;
  __syncthreads();

  const float gma = gamma_p[0];
  float invv[4][4];
#pragma unroll
  for (int mf = 0; mf < 4; ++mf)
#pragma unroll
    for (int r = 0; r < 4; ++r) invv[mf][r] = Sl[mf * 16 + l4 * 4 + r];

#pragma unroll
  for (int mf = 0; mf < 4; ++mf) {
    const int mb = m0 + mf * 16 + l4 * 4;
#pragma unroll
    for (int j = 0; j < 4; ++j) {
      const int c = cq + j * 16 + l15;
      float4 y;
      float* yp = (float*)&y;
#pragma unroll
      for (int r = 0; r < 4; ++r) {
        const float av = bf2f(abf[((size_t)b * N_ + mb + r) * C_ + c]);
        yp[r] = fmaxf(gma * acc[mf][j][r] * invv[mf][r] + av, 0.f);
      }
      *(float4*)&out[((size_t)b * C_ + c) * N_ + mb] = y;
    }
  }
}

// ---------------------------------------------------------------------------
extern "C" void kernel_launch(void* const* d_in, const int* in_sizes, int n_in,
                              void* d_out, int out_size, void* d_ws,
                              size_t ws_size, hipStream_t stream) {
  const float* x = (const float*)d_in[0];
  const float* dw1 = (const float*)d_in[1];
  const float* pw1 = (const float*)d_in[2];
  const float* bn1g = (const float*)d_in[3];
  const float* bn1b = (const float*)d_in[4];
  const float* bn1m = (const float*)d_in[5];
  const float* bn1v = (const float*)d_in[6];
  const float* dw2 = (const float*)d_in[7];
  const float* pw2 = (const float*)d_in[8];
  const float* bn2g = (const float*)d_in[9];
  const float* bn2b = (const float*)d_in[10];
  const float* bn2m = (const float*)d_in[11];
  const float* bn2v = (const float*)d_in[12];
  const float* wq = (const float*)d_in[13];
  const float* bq = (const float*)d_in[14];
  const float* wk = (const float*)d_in[15];
  const float* bk = (const float*)d_in[16];
  const float* wv = (const float*)d_in[17];
  const float* bv = (const float*)d_in[18];
  const float* gamma = (const float*)d_in[19];
  float* out = (float*)d_out;

  char* ws = (char*)d_ws;
  size_t off = 0;
  auto alloc = [&](size_t bytes) {
    void* p = ws + off;
    off += (bytes + 255) & ~(size_t)255;
    return p;
  };
  const size_t NE = (size_t)B_ * N_ * C_;  // 16.78M elements

  u16* bufA = (u16*)alloc(NE * 2);  // xt, later vchw
  u16* bufB = (u16*)alloc(NE * 2);  // t1, later t2
  u16* bufC = (u16*)alloc(NE * 2);  // y1, later qk
  u16* abf = (u16*)alloc(NE * 2);
  float* scale1 = (float*)alloc(256 * 4);
  float* shift1 = (float*)alloc(256 * 4);
  float* scale2 = (float*)alloc(256 * 4);
  float* shift2 = (float*)alloc(256 * 4);
  float* dwT1 = (float*)alloc(2304 * 4);
  float* dwT2 = (float*)alloc(2304 * 4);
  u16* pw1b = (u16*)alloc(65536 * 2);
  u16* pw2b = (u16*)alloc(65536 * 2);
  u16* wcatb = (u16*)alloc(81920 * 2);
  float* bcat = (float*)alloc(384 * 4);

  u16* xt = bufA;
  u16* t1 = bufB;
  u16* y1 = bufC;
  u16* t2 = bufB;
  u16* qkbuf = bufC;
  u16* vchw = bufA;

  prep<<<64, 256, 0, stream>>>(bn1g, bn1b, bn1m, bn1v, bn2g, bn2b, bn2m, bn2v,
                               wq, bq, wk, bk, wv, bv, pw1, pw2, dw1, dw2,
                               scale1, shift1, scale2, shift2, dwT1, dwT2,
                               pw1b, pw2b, wcatb, bcat);
  transpose_x<<<dim3(16, 4, B_), 256, 0, stream>>>(x, xt);
  dw_nhwc<<<dim3(128, B_), 256, 0, stream>>>(xt, dwT1, t1);
  gemm<0><<<dim3(8, 2, B_), 256, 0, stream>>>(t1, pw1b, scale1, shift1,
                                              nullptr, y1, nullptr);
  dw_nhwc<<<dim3(128, B_), 256, 0, stream>>>(y1, dwT2, t2);
  gemm<1><<<dim3(8, 2, B_), 256, 0, stream>>>(t2, pw2b, scale2, shift2, xt,
                                              abf, nullptr);
  gemm<2><<<dim3(8, 3, B_), 256, 0, stream>>>(abf, wcatb, nullptr, bcat,
                                              nullptr, qkbuf, vchw);
  flash<<<dim3(64, 16), 256, 0, stream>>>(qkbuf, vchw, abf, gamma, out);
}

// Round 14
// 252.045 us; speedup vs baseline: 1.1096x; 1.0170x over previous
//
#include <hip/hip_runtime.h>
#include <cstdint>
#include <cstddef>

#define B_ 64
#define C_ 256
#define N_ 1024
#define LOG2E 1.4426950408889634f

typedef short v8s __attribute__((ext_vector_type(8)));
typedef float v4f __attribute__((ext_vector_type(4)));
typedef unsigned int u32;
typedef unsigned short u16;

#define VMCNT(N) asm volatile("s_waitcnt vmcnt(" #N ")" ::: "memory")
#define LGKM0 asm volatile("s_waitcnt lgkmcnt(0)" ::: "memory")
#define SBAR __builtin_amdgcn_s_barrier()
#define SCHEDB __builtin_amdgcn_sched_barrier(0)

__device__ __forceinline__ float bf2f(u16 u) {
  return __uint_as_float(((u32)u) << 16);
}
__device__ __forceinline__ u16 f2bf(float f) {
  u32 x = __float_as_uint(f);
  x += 0x7fffu + ((x >> 16) & 1u);
  return (u16)(x >> 16);
}
__device__ __forceinline__ u32 pack2(float a, float b) {
  return (u32)f2bf(a) | ((u32)f2bf(b) << 16);
}
__device__ __forceinline__ u32 cvtpk(float lo, float hi) {
  u32 r;
  asm("v_cvt_pk_bf16_f32 %0, %1, %2" : "=v"(r) : "v"(lo), "v"(hi));
  return r;
}

typedef __attribute__((address_space(3))) unsigned int lds_as_t;
typedef __attribute__((address_space(1))) const unsigned int glb_as_t;
__device__ __forceinline__ void ld_lds16(const u16* g, u16* l) {
  __builtin_amdgcn_global_load_lds((glb_as_t*)g, (lds_as_t*)l, 16, 0, 0);
}

// ---------------------------------------------------------------------------
// prep: BN folding, weight casts / concat / transposes. q pre-scaled by log2e
// ---------------------------------------------------------------------------
__global__ __launch_bounds__(256) void prep(
    const float* __restrict__ g1, const float* __restrict__ b1,
    const float* __restrict__ m1, const float* __restrict__ v1,
    const float* __restrict__ g2, const float* __restrict__ b2,
    const float* __restrict__ m2, const float* __restrict__ v2,
    const float* __restrict__ wq, const float* __restrict__ bq,
    const float* __restrict__ wk, const float* __restrict__ bk,
    const float* __restrict__ wv, const float* __restrict__ bv,
    const float* __restrict__ pw1, const float* __restrict__ pw2,
    const float* __restrict__ dw1, const float* __restrict__ dw2,
    float* __restrict__ scale1, float* __restrict__ shift1,
    float* __restrict__ scale2, float* __restrict__ shift2,
    float* __restrict__ dwT1, float* __restrict__ dwT2,
    u16* __restrict__ pw1b, u16* __restrict__ pw2b, u16* __restrict__ wcatb,
    float* __restrict__ bcat) {
  const int gt = blockIdx.x * 256 + threadIdx.x;  // 16384 threads
  if (gt < 256) {
    float s1 = g1[gt] * rsqrtf(v1[gt] + 1e-5f);
    scale1[gt] = s1;
    shift1[gt] = b1[gt] - m1[gt] * s1;
    float s2 = g2[gt] * rsqrtf(v2[gt] + 1e-5f);
    scale2[gt] = s2;
    shift2[gt] = b2[gt] - m2[gt] * s2;
  }
  if (gt < 320)
    bcat[gt] = (gt < 32) ? bq[gt] * LOG2E
                         : (gt < 64) ? bk[gt - 32] : bv[gt - 64];
  if (gt < 2304) {
    dwT1[(gt % 9) * 256 + gt / 9] = dw1[gt];
    dwT2[(gt % 9) * 256 + gt / 9] = dw2[gt];
  }
  for (int e = gt; e < 65536; e += 16384) {
    pw1b[e] = f2bf(pw1[e]);
    pw2b[e] = f2bf(pw2[e]);
  }
  for (int e = gt; e < 81920; e += 16384) {
    const int o = e >> 8;
    float w = (o < 32) ? wq[e] * LOG2E
                       : (o < 64) ? wk[e - 8192] : wv[e - 16384];
    wcatb[e] = f2bf(w);
  }
}

// ---------------------------------------------------------------------------
// transpose x: [B][C][N] f32 -> [B][N][C] bf16  (64x64 tiles)
// ---------------------------------------------------------------------------
__global__ __launch_bounds__(256) void transpose_x(const float* __restrict__ x,
                                                   u16* __restrict__ xt) {
  __shared__ float t[64][65];
  const int b = blockIdx.z, c0 = blockIdx.y * 64, n0 = blockIdx.x * 64;
  const float* xp = x + ((size_t)b * C_ + c0) * N_ + n0;
  const int tn = threadIdx.x & 63, tc = threadIdx.x >> 6;
#pragma unroll
  for (int i = 0; i < 16; ++i)
    t[tc + 4 * i][tn] = xp[(size_t)(tc + 4 * i) * N_ + tn];
  __syncthreads();
  u16* op = xt + ((size_t)b * N_ + n0) * C_ + c0;
  const int oc = threadIdx.x & 63, on = threadIdx.x >> 6;
#pragma unroll
  for (int i = 0; i < 16; ++i)
    op[(size_t)(on + 4 * i) * C_ + oc] = f2bf(t[oc][on + 4 * i]);
}

// ---------------------------------------------------------------------------
// depthwise 3x3 NHWC bf16: src [B][N][C] -> dst [B][N][C]
// ---------------------------------------------------------------------------
__global__ __launch_bounds__(256) void dw_nhwc(const u16* __restrict__ src,
                                               const float* __restrict__ wT,
                                               u16* __restrict__ dst) {
  __shared__ float wl[9][256];
  const int b = blockIdx.y;
  for (int e = threadIdx.x; e < 2304; e += 256) wl[e >> 8][e & 255] = wT[e];
  __syncthreads();
  const int pl = threadIdx.x >> 5, c0 = (threadIdx.x & 31) * 8;
  const int p = blockIdx.x * 8 + pl;
  const int h = p >> 5, wx = p & 31;
  const u16* sp = src + (size_t)b * N_ * C_;
  float acc[8] = {0.f, 0.f, 0.f, 0.f, 0.f, 0.f, 0.f, 0.f};
#pragma unroll
  for (int dh = -1; dh <= 1; ++dh) {
    const int hh = h + dh;
    if (hh < 0 || hh > 31) continue;
#pragma unroll
    for (int dx = -1; dx <= 1; ++dx) {
      const int ww = wx + dx;
      if (ww < 0 || ww > 31) continue;
      const int k = (dh + 1) * 3 + (dx + 1);
      const uint4 v = *(const uint4*)(sp + (size_t)(hh * 32 + ww) * C_ + c0);
      const u32 vv[4] = {v.x, v.y, v.z, v.w};
#pragma unroll
      for (int j = 0; j < 4; ++j) {
        acc[2 * j] += bf2f((u16)(vv[j] & 0xffffu)) * wl[k][c0 + 2 * j];
        acc[2 * j + 1] += bf2f((u16)(vv[j] >> 16)) * wl[k][c0 + 2 * j + 1];
      }
    }
  }
  uint4 o4;
  o4.x = pack2(acc[0], acc[1]);
  o4.y = pack2(acc[2], acc[3]);
  o4.z = pack2(acc[4], acc[5]);
  o4.w = pack2(acc[6], acc[7]);
  *(uint4*)(dst + ((size_t)b * N_ + p) * C_ + c0) = o4;
}

// ---------------------------------------------------------------------------
// MFMA GEMM v3: BK=32 double-buffered gload_lds staging + counted vmcnt +
// raw barriers. LDS = 34.8KB -> 4 blocks/CU.
//   Y[n][o] = epi( sum_c X[n][c] * W[o][c] ), K = 256, tiles 128x128
// EPI 0: BN+ReLU -> bf16 NHWC (pw1)
// EPI 1: BN + bf16-NHWC residual -> bf16 NHWC (pw2)
// EPI 2: fused qkv (operands swapped so D rows = n):
//        o<64 -> qk [n][64] via LDS bounce; 64<=o<320 -> v CHW via bounce
// ---------------------------------------------------------------------------
template <int EPI>
__global__ __launch_bounds__(256, 4) void gemm(
    const u16* __restrict__ X, const u16* __restrict__ W,
    const float* __restrict__ scale, const float* __restrict__ shift,
    const u16* __restrict__ resid, u16* __restrict__ Y, u16* __restrict__ Y2) {
  __shared__ u16 smem[17408];  // 34.8KB: 2 x 16KB staging bufs; epi Ys 34KB
  u16(*Ys)[136] = (u16(*)[136])smem;
  u16(*YsQ)[68] = (u16(*)[68])smem;

  const int tid = threadIdx.x;
  const int b = blockIdx.z;
  const int n0 = blockIdx.x * 128, o0 = blockIdx.y * 128;
  const int wid = tid >> 6, lane = tid & 63;
  const int wn = wid & 1, wo = wid >> 1;
  const int l15 = lane & 15, l4 = lane >> 4;
  const int r16 = lane >> 2, c16 = (lane & 3) * 8;  // staging lane map

  v4f acc[4][4];
#pragma unroll
  for (int i = 0; i < 4; ++i)
#pragma unroll
    for (int j = 0; j < 4; ++j) acc[i][j] = v4f{0.f, 0.f, 0.f, 0.f};

  auto stage = [&](int kidx, int bufsel) {
    const int k0 = (kidx & 7) * 32;
    u16* Xd = smem + bufsel * 8192;
    u16* Wd = Xd + 4096;
#pragma unroll
    for (int g = 0; g < 2; ++g) {
      const int base = wid * 32 + g * 16;
      ld_lds16(X + ((size_t)b * N_ + n0 + base + r16) * C_ + k0 + c16,
               Xd + base * 32);
      int wr = o0 + base + r16;
      if (EPI == 2 && wr > 319) wr = 319;
      ld_lds16(W + (size_t)wr * C_ + k0 + c16, Wd + base * 32);
    }
  };

  stage(0, 0);
  stage(1, 1);

#pragma unroll
  for (int k = 0; k < 8; ++k) {
    const int cur = k & 1;
    if (k < 7) {
      VMCNT(4);
    } else {
      VMCNT(0);
    }
    SCHEDB;
    SBAR;
    const u16(*Xs)[32] = (const u16(*)[32])(smem + cur * 8192);
    const u16(*Ws)[32] = (const u16(*)[32])(smem + cur * 8192 + 4096);
    v8s af[4], bf4[4];
#pragma unroll
    for (int f = 0; f < 4; ++f) {
      if constexpr (EPI != 2) {
        af[f] = *(const v8s*)&Ws[wo * 64 + f * 16 + l15][l4 * 8];
        bf4[f] = *(const v8s*)&Xs[wn * 64 + f * 16 + l15][l4 * 8];
      } else {
        af[f] = *(const v8s*)&Xs[wn * 64 + f * 16 + l15][l4 * 8];
        bf4[f] = *(const v8s*)&Ws[wo * 64 + f * 16 + l15][l4 * 8];
      }
    }
#pragma unroll
    for (int i = 0; i < 4; ++i)
#pragma unroll
      for (int j = 0; j < 4; ++j)
        acc[i][j] = __builtin_amdgcn_mfma_f32_16x16x32_bf16(af[i], bf4[j],
                                                            acc[i][j], 0, 0, 0);
    LGKM0;
    SBAR;
    SCHEDB;
    if (k < 6) stage(k + 2, cur);
  }

  if constexpr (EPI != 2) {
#pragma unroll
    for (int i = 0; i < 4; ++i) {
      const int oL = wo * 64 + i * 16 + l4 * 4;
      const int o = o0 + oL;
      const float4 sc = *(const float4*)&scale[o];
      const float4 sh = *(const float4*)&shift[o];
#pragma unroll
      for (int j = 0; j < 4; ++j) {
        const int nL = wn * 64 + j * 16 + l15;
        float y0 = acc[i][j][0] * sc.x + sh.x;
        float y1 = acc[i][j][1] * sc.y + sh.y;
        float y2 = acc[i][j][2] * sc.z + sh.z;
        float y3 = acc[i][j][3] * sc.w + sh.w;
        if constexpr (EPI == 0) {
          y0 = fmaxf(y0, 0.f);
          y1 = fmaxf(y1, 0.f);
          y2 = fmaxf(y2, 0.f);
          y3 = fmaxf(y3, 0.f);
        } else {
          const uint2 rb =
              *(const uint2*)(resid + ((size_t)b * N_ + n0 + nL) * C_ + o);
          y0 += bf2f((u16)(rb.x & 0xffffu));
          y1 += bf2f((u16)(rb.x >> 16));
          y2 += bf2f((u16)(rb.y & 0xffffu));
          y3 += bf2f((u16)(rb.y >> 16));
        }
        uint2 st;
        st.x = pack2(y0, y1);
        st.y = pack2(y2, y3);
        *(uint2*)&Ys[nL][oL] = st;
      }
    }
    __syncthreads();
#pragma unroll
    for (int s = 0; s < 8; ++s) {
      const int nL = s * 16 + (tid >> 4);
      const int slot = tid & 15;
      const uint4 v = *(const uint4*)&Ys[nL][slot * 8];
      *(uint4*)&Y[((size_t)b * N_ + n0 + nL) * C_ + o0 + slot * 8] = v;
    }
  } else {
    float bj[4];
#pragma unroll
    for (int j = 0; j < 4; ++j) {
      int o = o0 + wo * 64 + j * 16 + l15;
      bj[j] = shift[o > 319 ? 319 : o];
    }
    if (o0 == 0 && wo == 0) {
#pragma unroll
      for (int i = 0; i < 4; ++i) {
        const int nL = wn * 64 + i * 16 + l4 * 4;
#pragma unroll
        for (int j = 0; j < 4; ++j) {
          const int oL = j * 16 + l15;
#pragma unroll
          for (int r = 0; r < 4; ++r)
            YsQ[nL + r][oL] = f2bf(acc[i][j][r] + bj[j]);
        }
      }
    } else {
#pragma unroll
      for (int i = 0; i < 4; ++i) {
        const int nL = wn * 64 + i * 16 + l4 * 4;
#pragma unroll
        for (int j = 0; j < 4; ++j) {
          const int oL = wo * 64 + j * 16 + l15;
          uint2 st;
          st.x = pack2(acc[i][j][0] + bj[j], acc[i][j][1] + bj[j]);
          st.y = pack2(acc[i][j][2] + bj[j], acc[i][j][3] + bj[j]);
          *(uint2*)&Ys[oL][nL] = st;
        }
      }
    }
    __syncthreads();
    if (o0 == 0) {
#pragma unroll
      for (int s = 0; s < 4; ++s) {
        const int e = s * 256 + tid;
        const int row = e >> 3, seg = e & 7;
        const uint4 v = *(const uint4*)&YsQ[row][seg * 8];
        *(uint4*)&Y[((size_t)b * N_ + n0 + row) * 64 + seg * 8] = v;
      }
#pragma unroll
      for (int s = 0; s < 4; ++s) {
        const int e = s * 256 + tid;
        const int oL = 64 + (e >> 4), slot = e & 15;
        const uint4 v = *(const uint4*)&Ys[oL][slot * 8];
        *(uint4*)&Y2[((size_t)b * C_ + oL - 64) * N_ + n0 + slot * 8] = v;
      }
    } else {
#pragma unroll
      for (int s = 0; s < 8; ++s) {
        const int oL = s * 16 + (tid >> 4);
        const int c = o0 + oL - 64;
        if (c < 256) {
          const int slot = tid & 15;
          const uint4 v = *(const uint4*)&Ys[oL][slot * 8];
          *(uint4*)&Y2[((size_t)b * C_ + c) * N_ + n0 + slot * 8] = v;
        }
      }
    }
  }
}

// ---------------------------------------------------------------------------
// flash v9: pipelined pass 2 — phase t issues QK^T(t) AND PV(t-1) in one
// barrier period; exp2(t) overlaps the MFMA drain. c-split PV, wave-private
// V quarters (single buffer), Pl double-buffered (producer t, consumer t+1).
// ---------------------------------------------------------------------------
__global__ __launch_bounds__(256, 3) void flash(
    const u16* __restrict__ qk, const u16* __restrict__ vchw,
    const u16* __restrict__ abf, const float* __restrict__ gamma_p,
    float* __restrict__ out) {
  const int b = blockIdx.x;
  const int m0 = blockIdx.y * 64;
  const int tid = threadIdx.x, wid = tid >> 6, lane = tid & 63;
  const int l15 = lane & 15, l4 = lane >> 4;
  const int mw = m0 + wid * 16;
  const int cq = wid * 64;  // this wave's private c-quarter

  __shared__ u16 Vs[256][64];    // linear rows (gload_lds dest), src-swizzled
  __shared__ u16 Pl[2][64][72];  // P [m][n], double-buffered, pad-72
  __shared__ float Sl[64];

  const u16* qkb = qk + (size_t)b * N_ * 64;
  const u16* vb = vchw + (size_t)b * C_ * N_;
  const v8s qf = *(const v8s*)&qkb[(size_t)(mw + l15) * 64 + l4 * 8];

  const int s_row = lane >> 3;               // 0..7
  const int s_j = (lane & 7) ^ (s_row & 7);  // pre-swizzled global slot

  // ---- pass 1: exact row max (m-split waves, n-blocks of 64) ----
  float Mloc = -3e38f;
  {
    v8s kf1[4];
#pragma unroll
    for (int f = 0; f < 4; ++f)
      kf1[f] = *(const v8s*)&qkb[(size_t)(f * 16 + l15) * 64 + 32 + l4 * 8];
    for (int t = 0; t < 16; ++t) {
      v8s kn[4];
      if (t < 15) {
        const int n1 = (t + 1) * 64;
#pragma unroll
        for (int f = 0; f < 4; ++f)
          kn[f] =
              *(const v8s*)&qkb[(size_t)(n1 + f * 16 + l15) * 64 + 32 + l4 * 8];
      }
#pragma unroll
      for (int f = 0; f < 4; ++f) {
        const v4f lt = __builtin_amdgcn_mfma_f32_16x16x32_bf16(
            kf1[f], qf, v4f{0.f, 0.f, 0.f, 0.f}, 0, 0, 0);
        Mloc = fmaxf(Mloc, fmaxf(fmaxf(lt[0], lt[1]), fmaxf(lt[2], lt[3])));
      }
      if (t < 15) {
#pragma unroll
        for (int f = 0; f < 4; ++f) kf1[f] = kn[f];
      }
    }
  }
  Mloc = fmaxf(Mloc, __shfl_xor(Mloc, 16));
  Mloc = fmaxf(Mloc, __shfl_xor(Mloc, 32));
  const float M = Mloc;

  // ---- pass 2 (pipelined) ----
  v4f acc[4][4];
#pragma unroll
  for (int mf = 0; mf < 4; ++mf)
#pragma unroll
    for (int j = 0; j < 4; ++j) acc[mf][j] = v4f{0.f, 0.f, 0.f, 0.f};
  float S0 = 0.f, S1 = 0.f, S2 = 0.f, S3 = 0.f;
  v8s kf[4];
#pragma unroll
  for (int f = 0; f < 4; ++f)
    kf[f] = *(const v8s*)&qkb[(size_t)(f * 16 + l15) * 64 + 32 + l4 * 8];
  VMCNT(0);  // pass-1 loads + kf(0) drained
  SCHEDB;

  // phase 0: QK^T(0) -> exp2 -> Pl[0]; kf(1); stage V(0)
  {
    v4f lt[4];
#pragma unroll
    for (int f = 0; f < 4; ++f)
      lt[f] = __builtin_amdgcn_mfma_f32_16x16x32_bf16(
          kf[f], qf, v4f{0.f, 0.f, 0.f, 0.f}, 0, 0, 0);
#pragma unroll
    for (int f = 0; f < 4; ++f) {
      const float p0 = exp2f(lt[f][0] - M);
      const float p1 = exp2f(lt[f][1] - M);
      const float p2 = exp2f(lt[f][2] - M);
      const float p3 = exp2f(lt[f][3] - M);
      S0 += p0;
      S1 += p1;
      S2 += p2;
      S3 += p3;
      uint2 pw;
      pw.x = cvtpk(p0, p1);
      pw.y = cvtpk(p2, p3);
      *(uint2*)&Pl[0][wid * 16 + l15][f * 16 + l4 * 4] = pw;
    }
#pragma unroll
    for (int f = 0; f < 4; ++f)
      kf[f] = *(const v8s*)&qkb[(size_t)(64 + f * 16 + l15) * 64 + 32 + l4 * 8];
    SCHEDB;
#pragma unroll
    for (int g = 0; g < 8; ++g) {
      const int base = cq + g * 8;
      ld_lds16(vb + (size_t)(base + s_row) * N_ + s_j * 8, &Vs[base][0]);
    }
    LGKM0;
    SBAR;
  }

  // phases 1..15: QK^T(t) + PV(t-1); exp2(t); kf(t+1); stage V(t)
  for (int t = 1; t < 16; ++t) {
    const int pb = (t - 1) & 1, cb = t & 1;
    VMCNT(8);  // kf(t) (4 oldest) landed; V(t-1) stage (8 newest) may fly
    SCHEDB;
    v4f lt[4];
#pragma unroll
    for (int f = 0; f < 4; ++f)
      lt[f] = __builtin_amdgcn_mfma_f32_16x16x32_bf16(
          kf[f], qf, v4f{0.f, 0.f, 0.f, 0.f}, 0, 0, 0);
    VMCNT(0);  // V(t-1) landed in own quarter
    SCHEDB;
    __builtin_amdgcn_s_setprio(1);
#pragma unroll
    for (int ks = 0; ks < 2; ++ks) {
      v8s pa[4];
#pragma unroll
      for (int mf = 0; mf < 4; ++mf)
        pa[mf] = *(const v8s*)&Pl[pb][mf * 16 + l15][ks * 32 + l4 * 8];
#pragma unroll
      for (int j = 0; j < 4; ++j) {
        const int col = 8 * (((ks * 4) + l4) ^ (l15 & 7));
        const v8s vf = *(const v8s*)&Vs[cq + j * 16 + l15][col];
#pragma unroll
        for (int mf = 0; mf < 4; ++mf)
          acc[mf][j] = __builtin_amdgcn_mfma_f32_16x16x32_bf16(
              pa[mf], vf, acc[mf][j], 0, 0, 0);
      }
    }
    __builtin_amdgcn_s_setprio(0);
    // exp2(t) -> Pl[cb] (lt ready since phase start; overlaps MFMA drain)
#pragma unroll
    for (int f = 0; f < 4; ++f) {
      const float p0 = exp2f(lt[f][0] - M);
      const float p1 = exp2f(lt[f][1] - M);
      const float p2 = exp2f(lt[f][2] - M);
      const float p3 = exp2f(lt[f][3] - M);
      S0 += p0;
      S1 += p1;
      S2 += p2;
      S3 += p3;
      uint2 pw;
      pw.x = cvtpk(p0, p1);
      pw.y = cvtpk(p2, p3);
      *(uint2*)&Pl[cb][wid * 16 + l15][f * 16 + l4 * 4] = pw;
    }
    // kf(t+1) (wrap keeps vmcnt counts uniform)
    {
      const int n1 = ((t + 1) & 15) * 64;
#pragma unroll
      for (int f = 0; f < 4; ++f)
        kf[f] =
            *(const v8s*)&qkb[(size_t)(n1 + f * 16 + l15) * 64 + 32 + l4 * 8];
    }
    SCHEDB;
    // stage V(t) into own quarter (after own PV reads of V(t-1))
    {
      const int n1 = t * 64;
#pragma unroll
      for (int g = 0; g < 8; ++g) {
        const int base = cq + g * 8;
        ld_lds16(vb + (size_t)(base + s_row) * N_ + n1 + s_j * 8, &Vs[base][0]);
      }
    }
    LGKM0;  // P(t) writes retired -> visible after barrier
    SBAR;
  }

  // epilogue: PV(15) using Pl[1] and V(15)
  VMCNT(0);
  SCHEDB;
  __builtin_amdgcn_s_setprio(1);
#pragma unroll
  for (int ks = 0; ks < 2; ++ks) {
    v8s pa[4];
#pragma unroll
    for (int mf = 0; mf < 4; ++mf)
      pa[mf] = *(const v8s*)&Pl[1][mf * 16 + l15][ks * 32 + l4 * 8];
#pragma unroll
    for (int j = 0; j < 4; ++j) {
      const int col = 8 * (((ks * 4) + l4) ^ (l15 & 7));
      const v8s vf = *(const v8s*)&Vs[cq + j * 16 + l15][col];
#pragma unroll
      for (int mf = 0; mf < 4; ++mf)
        acc[mf][j] = __builtin_amdgcn_mfma_f32_16x16x32_bf16(
            pa[mf], vf, acc[mf][j], 0, 0, 0);
    }
  }
  __builtin_amdgcn_s_setprio(0);

  float S = (S0 + S1) + (S2 + S3);
  S += __shfl_xor(S, 16);
  S += __shfl_xor(S, 32);
  if (lane < 16) Sl[wid * 16 + lane] = 1.f / S;
  __syncthreads();

  const float gma = gamma_p[0];
  float invv[4][4];
#pragma unroll
  for (int mf = 0; mf < 4; ++mf)
#pragma unroll
    for (int r = 0; r < 4; ++r) invv[mf][r] = Sl[mf * 16 + l4 * 4 + r];

#pragma unroll
  for (int mf = 0; mf < 4; ++mf) {
    const int mb = m0 + mf * 16 + l4 * 4;
#pragma unroll
    for (int j = 0; j < 4; ++j) {
      const int c = cq + j * 16 + l15;
      float4 y;
      float* yp = (float*)&y;
#pragma unroll
      for (int r = 0; r < 4; ++r) {
        const float av = bf2f(abf[((size_t)b * N_ + mb + r) * C_ + c]);
        yp[r] = fmaxf(gma * acc[mf][j][r] * invv[mf][r] + av, 0.f);
      }
      *(float4*)&out[((size_t)b * C_ + c) * N_ + mb] = y;
    }
  }
}

// ---------------------------------------------------------------------------
extern "C" void kernel_launch(void* const* d_in, const int* in_sizes, int n_in,
                              void* d_out, int out_size, void* d_ws,
                              size_t ws_size, hipStream_t stream) {
  const float* x = (const float*)d_in[0];
  const float* dw1 = (const float*)d_in[1];
  const float* pw1 = (const float*)d_in[2];
  const float* bn1g = (const float*)d_in[3];
  const float* bn1b = (const float*)d_in[4];
  const float* bn1m = (const float*)d_in[5];
  const float* bn1v = (const float*)d_in[6];
  const float* dw2 = (const float*)d_in[7];
  const float* pw2 = (const float*)d_in[8];
  const float* bn2g = (const float*)d_in[9];
  const float* bn2b = (const float*)d_in[10];
  const float* bn2m = (const float*)d_in[11];
  const float* bn2v = (const float*)d_in[12];
  const float* wq = (const float*)d_in[13];
  const float* bq = (const float*)d_in[14];
  const float* wk = (const float*)d_in[15];
  const float* bk = (const float*)d_in[16];
  const float* wv = (const float*)d_in[17];
  const float* bv = (const float*)d_in[18];
  const float* gamma = (const float*)d_in[19];
  float* out = (float*)d_out;

  char* ws = (char*)d_ws;
  size_t off = 0;
  auto alloc = [&](size_t bytes) {
    void* p = ws + off;
    off += (bytes + 255) & ~(size_t)255;
    return p;
  };
  const size_t NE = (size_t)B_ * N_ * C_;  // 16.78M elements

  u16* bufA = (u16*)alloc(NE * 2);  // xt, later vchw
  u16* bufB = (u16*)alloc(NE * 2);  // t1, later t2
  u16* bufC = (u16*)alloc(NE * 2);  // y1, later qk
  u16* abf = (u16*)alloc(NE * 2);
  float* scale1 = (float*)alloc(256 * 4);
  float* shift1 = (float*)alloc(256 * 4);
  float* scale2 = (float*)alloc(256 * 4);
  float* shift2 = (float*)alloc(256 * 4);
  float* dwT1 = (float*)alloc(2304 * 4);
  float* dwT2 = (float*)alloc(2304 * 4);
  u16* pw1b = (u16*)alloc(65536 * 2);
  u16* pw2b = (u16*)alloc(65536 * 2);
  u16* wcatb = (u16*)alloc(81920 * 2);
  float* bcat = (float*)alloc(384 * 4);

  u16* xt = bufA;
  u16* t1 = bufB;
  u16* y1 = bufC;
  u16* t2 = bufB;
  u16* qkbuf = bufC;
  u16* vchw = bufA;

  prep<<<64, 256, 0, stream>>>(bn1g, bn1b, bn1m, bn1v, bn2g, bn2b, bn2m, bn2v,
                               wq, bq, wk, bk, wv, bv, pw1, pw2, dw1, dw2,
                               scale1, shift1, scale2, shift2, dwT1, dwT2,
                               pw1b, pw2b, wcatb, bcat);
  transpose_x<<<dim3(16, 4, B_), 256, 0, stream>>>(x, xt);
  dw_nhwc<<<dim3(128, B_), 256, 0, stream>>>(xt, dwT1, t1);
  gemm<0><<<dim3(8, 2, B_), 256, 0, stream>>>(t1, pw1b, scale1, shift1,
                                              nullptr, y1, nullptr);
  dw_nhwc<<<dim3(128, B_), 256, 0, stream>>>(y1, dwT2, t2);
  gemm<1><<<dim3(8, 2, B_), 256, 0, stream>>>(t2, pw2b, scale2, shift2, xt,
                                              abf, nullptr);
  gemm<2><<<dim3(8, 3, B_), 256, 0, stream>>>(abf, wcatb, nullptr, bcat,
                                              nullptr, qkbuf, vchw);
  flash<<<dim3(64, 16), 256, 0, stream>>>(qkbuf, vchw, abf, gamma, out);
}

// Round 15
// 231.043 us; speedup vs baseline: 1.2104x; 1.0909x over previous
//
#include <hip/hip_runtime.h>
#include <cstdint>
#include <cstddef>

#define B_ 64
#define C_ 256
#define N_ 1024
#define LOG2E 1.4426950408889634f

typedef short v8s __attribute__((ext_vector_type(8)));
typedef float v4f __attribute__((ext_vector_type(4)));
typedef unsigned int u32;
typedef unsigned short u16;

#define VMCNT(N) asm volatile("s_waitcnt vmcnt(" #N ")" ::: "memory")
#define LGKM0 asm volatile("s_waitcnt lgkmcnt(0)" ::: "memory")
#define SBAR __builtin_amdgcn_s_barrier()
#define SCHEDB __builtin_amdgcn_sched_barrier(0)

__device__ __forceinline__ float bf2f(u16 u) {
  return __uint_as_float(((u32)u) << 16);
}
__device__ __forceinline__ u16 f2bf(float f) {
  u32 x = __float_as_uint(f);
  x += 0x7fffu + ((x >> 16) & 1u);
  return (u16)(x >> 16);
}
__device__ __forceinline__ u32 pack2(float a, float b) {
  return (u32)f2bf(a) | ((u32)f2bf(b) << 16);
}
__device__ __forceinline__ u32 cvtpk(float lo, float hi) {
  u32 r;
  asm("v_cvt_pk_bf16_f32 %0, %1, %2" : "=v"(r) : "v"(lo), "v"(hi));
  return r;
}

typedef __attribute__((address_space(3))) unsigned int lds_as_t;
typedef __attribute__((address_space(1))) const unsigned int glb_as_t;
__device__ __forceinline__ void ld_lds16(const u16* g, u16* l) {
  __builtin_amdgcn_global_load_lds((glb_as_t*)g, (lds_as_t*)l, 16, 0, 0);
}

// ---------------------------------------------------------------------------
// prep: BN folding, weight casts / concat / transposes. q pre-scaled by log2e
// ---------------------------------------------------------------------------
__global__ __launch_bounds__(256) void prep(
    const float* __restrict__ g1, const float* __restrict__ b1,
    const float* __restrict__ m1, const float* __restrict__ v1,
    const float* __restrict__ g2, const float* __restrict__ b2,
    const float* __restrict__ m2, const float* __restrict__ v2,
    const float* __restrict__ wq, const float* __restrict__ bq,
    const float* __restrict__ wk, const float* __restrict__ bk,
    const float* __restrict__ wv, const float* __restrict__ bv,
    const float* __restrict__ pw1, const float* __restrict__ pw2,
    const float* __restrict__ dw1, const float* __restrict__ dw2,
    float* __restrict__ scale1, float* __restrict__ shift1,
    float* __restrict__ scale2, float* __restrict__ shift2,
    float* __restrict__ dwT1, float* __restrict__ dwT2,
    u16* __restrict__ pw1b, u16* __restrict__ pw2b, u16* __restrict__ wcatb,
    float* __restrict__ bcat) {
  const int gt = blockIdx.x * 256 + threadIdx.x;  // 16384 threads
  if (gt < 256) {
    float s1 = g1[gt] * rsqrtf(v1[gt] + 1e-5f);
    scale1[gt] = s1;
    shift1[gt] = b1[gt] - m1[gt] * s1;
    float s2 = g2[gt] * rsqrtf(v2[gt] + 1e-5f);
    scale2[gt] = s2;
    shift2[gt] = b2[gt] - m2[gt] * s2;
  }
  if (gt < 320)
    bcat[gt] = (gt < 32) ? bq[gt] * LOG2E
                         : (gt < 64) ? bk[gt - 32] : bv[gt - 64];
  if (gt < 2304) {
    dwT1[(gt % 9) * 256 + gt / 9] = dw1[gt];
    dwT2[(gt % 9) * 256 + gt / 9] = dw2[gt];
  }
  for (int e = gt; e < 65536; e += 16384) {
    pw1b[e] = f2bf(pw1[e]);
    pw2b[e] = f2bf(pw2[e]);
  }
  for (int e = gt; e < 81920; e += 16384) {
    const int o = e >> 8;
    float w = (o < 32) ? wq[e] * LOG2E
                       : (o < 64) ? wk[e - 8192] : wv[e - 16384];
    wcatb[e] = f2bf(w);
  }
}

// ---------------------------------------------------------------------------
// transpose x: [B][C][N] f32 -> [B][N][C] bf16  (64x64 tiles)
// ---------------------------------------------------------------------------
__global__ __launch_bounds__(256) void transpose_x(const float* __restrict__ x,
                                                   u16* __restrict__ xt) {
  __shared__ float t[64][65];
  const int b = blockIdx.z, c0 = blockIdx.y * 64, n0 = blockIdx.x * 64;
  const float* xp = x + ((size_t)b * C_ + c0) * N_ + n0;
  const int tn = threadIdx.x & 63, tc = threadIdx.x >> 6;
#pragma unroll
  for (int i = 0; i < 16; ++i)
    t[tc + 4 * i][tn] = xp[(size_t)(tc + 4 * i) * N_ + tn];
  __syncthreads();
  u16* op = xt + ((size_t)b * N_ + n0) * C_ + c0;
  const int oc = threadIdx.x & 63, on = threadIdx.x >> 6;
#pragma unroll
  for (int i = 0; i < 16; ++i)
    op[(size_t)(on + 4 * i) * C_ + oc] = f2bf(t[oc][on + 4 * i]);
}

// ---------------------------------------------------------------------------
// depthwise 3x3 NHWC bf16: src [B][N][C] -> dst [B][N][C]
// ---------------------------------------------------------------------------
__global__ __launch_bounds__(256) void dw_nhwc(const u16* __restrict__ src,
                                               const float* __restrict__ wT,
                                               u16* __restrict__ dst) {
  __shared__ float wl[9][256];
  const int b = blockIdx.y;
  for (int e = threadIdx.x; e < 2304; e += 256) wl[e >> 8][e & 255] = wT[e];
  __syncthreads();
  const int pl = threadIdx.x >> 5, c0 = (threadIdx.x & 31) * 8;
  const int p = blockIdx.x * 8 + pl;
  const int h = p >> 5, wx = p & 31;
  const u16* sp = src + (size_t)b * N_ * C_;
  float acc[8] = {0.f, 0.f, 0.f, 0.f, 0.f, 0.f, 0.f, 0.f};
#pragma unroll
  for (int dh = -1; dh <= 1; ++dh) {
    const int hh = h + dh;
    if (hh < 0 || hh > 31) continue;
#pragma unroll
    for (int dx = -1; dx <= 1; ++dx) {
      const int ww = wx + dx;
      if (ww < 0 || ww > 31) continue;
      const int k = (dh + 1) * 3 + (dx + 1);
      const uint4 v = *(const uint4*)(sp + (size_t)(hh * 32 + ww) * C_ + c0);
      const u32 vv[4] = {v.x, v.y, v.z, v.w};
#pragma unroll
      for (int j = 0; j < 4; ++j) {
        acc[2 * j] += bf2f((u16)(vv[j] & 0xffffu)) * wl[k][c0 + 2 * j];
        acc[2 * j + 1] += bf2f((u16)(vv[j] >> 16)) * wl[k][c0 + 2 * j + 1];
      }
    }
  }
  uint4 o4;
  o4.x = pack2(acc[0], acc[1]);
  o4.y = pack2(acc[2], acc[3]);
  o4.z = pack2(acc[4], acc[5]);
  o4.w = pack2(acc[6], acc[7]);
  *(uint4*)(dst + ((size_t)b * N_ + p) * C_ + c0) = o4;
}

// ---------------------------------------------------------------------------
// MFMA GEMM v3: BK=32 double-buffered gload_lds staging + counted vmcnt +
// raw barriers. LDS = 34.8KB -> 4 blocks/CU.
// ---------------------------------------------------------------------------
template <int EPI>
__global__ __launch_bounds__(256, 4) void gemm(
    const u16* __restrict__ X, const u16* __restrict__ W,
    const float* __restrict__ scale, const float* __restrict__ shift,
    const u16* __restrict__ resid, u16* __restrict__ Y, u16* __restrict__ Y2) {
  __shared__ u16 smem[17408];  // 34.8KB: 2 x 16KB staging bufs; epi Ys 34KB
  u16(*Ys)[136] = (u16(*)[136])smem;
  u16(*YsQ)[68] = (u16(*)[68])smem;

  const int tid = threadIdx.x;
  const int b = blockIdx.z;
  const int n0 = blockIdx.x * 128, o0 = blockIdx.y * 128;
  const int wid = tid >> 6, lane = tid & 63;
  const int wn = wid & 1, wo = wid >> 1;
  const int l15 = lane & 15, l4 = lane >> 4;
  const int r16 = lane >> 2, c16 = (lane & 3) * 8;  // staging lane map

  v4f acc[4][4];
#pragma unroll
  for (int i = 0; i < 4; ++i)
#pragma unroll
    for (int j = 0; j < 4; ++j) acc[i][j] = v4f{0.f, 0.f, 0.f, 0.f};

  auto stage = [&](int kidx, int bufsel) {
    const int k0 = (kidx & 7) * 32;
    u16* Xd = smem + bufsel * 8192;
    u16* Wd = Xd + 4096;
#pragma unroll
    for (int g = 0; g < 2; ++g) {
      const int base = wid * 32 + g * 16;
      ld_lds16(X + ((size_t)b * N_ + n0 + base + r16) * C_ + k0 + c16,
               Xd + base * 32);
      int wr = o0 + base + r16;
      if (EPI == 2 && wr > 319) wr = 319;
      ld_lds16(W + (size_t)wr * C_ + k0 + c16, Wd + base * 32);
    }
  };

  stage(0, 0);
  stage(1, 1);

#pragma unroll
  for (int k = 0; k < 8; ++k) {
    const int cur = k & 1;
    if (k < 7) {
      VMCNT(4);
    } else {
      VMCNT(0);
    }
    SCHEDB;
    SBAR;
    const u16(*Xs)[32] = (const u16(*)[32])(smem + cur * 8192);
    const u16(*Ws)[32] = (const u16(*)[32])(smem + cur * 8192 + 4096);
    v8s af[4], bf4[4];
#pragma unroll
    for (int f = 0; f < 4; ++f) {
      if constexpr (EPI != 2) {
        af[f] = *(const v8s*)&Ws[wo * 64 + f * 16 + l15][l4 * 8];
        bf4[f] = *(const v8s*)&Xs[wn * 64 + f * 16 + l15][l4 * 8];
      } else {
        af[f] = *(const v8s*)&Xs[wn * 64 + f * 16 + l15][l4 * 8];
        bf4[f] = *(const v8s*)&Ws[wo * 64 + f * 16 + l15][l4 * 8];
      }
    }
#pragma unroll
    for (int i = 0; i < 4; ++i)
#pragma unroll
      for (int j = 0; j < 4; ++j)
        acc[i][j] = __builtin_amdgcn_mfma_f32_16x16x32_bf16(af[i], bf4[j],
                                                            acc[i][j], 0, 0, 0);
    LGKM0;
    SBAR;
    SCHEDB;
    if (k < 6) stage(k + 2, cur);
  }

  if constexpr (EPI != 2) {
#pragma unroll
    for (int i = 0; i < 4; ++i) {
      const int oL = wo * 64 + i * 16 + l4 * 4;
      const int o = o0 + oL;
      const float4 sc = *(const float4*)&scale[o];
      const float4 sh = *(const float4*)&shift[o];
#pragma unroll
      for (int j = 0; j < 4; ++j) {
        const int nL = wn * 64 + j * 16 + l15;
        float y0 = acc[i][j][0] * sc.x + sh.x;
        float y1 = acc[i][j][1] * sc.y + sh.y;
        float y2 = acc[i][j][2] * sc.z + sh.z;
        float y3 = acc[i][j][3] * sc.w + sh.w;
        if constexpr (EPI == 0) {
          y0 = fmaxf(y0, 0.f);
          y1 = fmaxf(y1, 0.f);
          y2 = fmaxf(y2, 0.f);
          y3 = fmaxf(y3, 0.f);
        } else {
          const uint2 rb =
              *(const uint2*)(resid + ((size_t)b * N_ + n0 + nL) * C_ + o);
          y0 += bf2f((u16)(rb.x & 0xffffu));
          y1 += bf2f((u16)(rb.x >> 16));
          y2 += bf2f((u16)(rb.y & 0xffffu));
          y3 += bf2f((u16)(rb.y >> 16));
        }
        uint2 st;
        st.x = pack2(y0, y1);
        st.y = pack2(y2, y3);
        *(uint2*)&Ys[nL][oL] = st;
      }
    }
    __syncthreads();
#pragma unroll
    for (int s = 0; s < 8; ++s) {
      const int nL = s * 16 + (tid >> 4);
      const int slot = tid & 15;
      const uint4 v = *(const uint4*)&Ys[nL][slot * 8];
      *(uint4*)&Y[((size_t)b * N_ + n0 + nL) * C_ + o0 + slot * 8] = v;
    }
  } else {
    float bj[4];
#pragma unroll
    for (int j = 0; j < 4; ++j) {
      int o = o0 + wo * 64 + j * 16 + l15;
      bj[j] = shift[o > 319 ? 319 : o];
    }
    if (o0 == 0 && wo == 0) {
#pragma unroll
      for (int i = 0; i < 4; ++i) {
        const int nL = wn * 64 + i * 16 + l4 * 4;
#pragma unroll
        for (int j = 0; j < 4; ++j) {
          const int oL = j * 16 + l15;
#pragma unroll
          for (int r = 0; r < 4; ++r)
            YsQ[nL + r][oL] = f2bf(acc[i][j][r] + bj[j]);
        }
      }
    } else {
#pragma unroll
      for (int i = 0; i < 4; ++i) {
        const int nL = wn * 64 + i * 16 + l4 * 4;
#pragma unroll
        for (int j = 0; j < 4; ++j) {
          const int oL = wo * 64 + j * 16 + l15;
          uint2 st;
          st.x = pack2(acc[i][j][0] + bj[j], acc[i][j][1] + bj[j]);
          st.y = pack2(acc[i][j][2] + bj[j], acc[i][j][3] + bj[j]);
          *(uint2*)&Ys[oL][nL] = st;
        }
      }
    }
    __syncthreads();
    if (o0 == 0) {
#pragma unroll
      for (int s = 0; s < 4; ++s) {
        const int e = s * 256 + tid;
        const int row = e >> 3, seg = e & 7;
        const uint4 v = *(const uint4*)&YsQ[row][seg * 8];
        *(uint4*)&Y[((size_t)b * N_ + n0 + row) * 64 + seg * 8] = v;
      }
#pragma unroll
      for (int s = 0; s < 4; ++s) {
        const int e = s * 256 + tid;
        const int oL = 64 + (e >> 4), slot = e & 15;
        const uint4 v = *(const uint4*)&Ys[oL][slot * 8];
        *(uint4*)&Y2[((size_t)b * C_ + oL - 64) * N_ + n0 + slot * 8] = v;
      }
    } else {
#pragma unroll
      for (int s = 0; s < 8; ++s) {
        const int oL = s * 16 + (tid >> 4);
        const int c = o0 + oL - 64;
        if (c < 256) {
          const int slot = tid & 15;
          const uint4 v = *(const uint4*)&Ys[oL][slot * 8];
          *(uint4*)&Y2[((size_t)b * C_ + c) * N_ + n0 + slot * 8] = v;
        }
      }
    }
  }
}

// ---------------------------------------------------------------------------
// flash v10: SINGLE-PASS online softmax on the pipelined v9 skeleton.
// Phase t: QK^T(t) -> acc *= fscL[t-1] -> PV(t-1) -> online M/S update,
// exp2 -> Pl[t&1] + publish fsc -> kf(t+1) -> stage V(t) -> barrier.
// Epilogue: final rescale + PV(15); abf bounced through LDS (coalesced).
// ---------------------------------------------------------------------------
__global__ __launch_bounds__(256, 3) void flash(
    const u16* __restrict__ qk, const u16* __restrict__ vchw,
    const u16* __restrict__ abf, const float* __restrict__ gamma_p,
    float* __restrict__ out) {
  const int b = blockIdx.x;
  const int m0 = blockIdx.y * 64;
  const int tid = threadIdx.x, wid = tid >> 6, lane = tid & 63;
  const int l15 = lane & 15, l4 = lane >> 4;
  const int mw = m0 + wid * 16;
  const int cq = wid * 64;  // this wave's private c-quarter

  // 51.2KB aliased pool: Vs [256][64] u16 (32KB) + Pl[2][64][72] (18.4KB);
  // epilogue reuses it as AB [64][264] bf16 (abf tile).
  __shared__ u16 pool[25600];
  __shared__ float fscL[2][64];
  __shared__ float Sl[64];
  u16(*Vs)[64] = (u16(*)[64])pool;
  u16(*Pl)[64][72] = (u16(*)[64][72])(pool + 16384);
  u16* AB = pool;  // [64][264]

  const u16* qkb = qk + (size_t)b * N_ * 64;
  const u16* vb = vchw + (size_t)b * C_ * N_;
  const v8s qf = *(const v8s*)&qkb[(size_t)(mw + l15) * 64 + l4 * 8];

  const int s_row = lane >> 3;               // 0..7
  const int s_j = (lane & 7) ^ (s_row & 7);  // pre-swizzled global slot

  v4f acc[4][4];
#pragma unroll
  for (int mf = 0; mf < 4; ++mf)
#pragma unroll
    for (int j = 0; j < 4; ++j) acc[mf][j] = v4f{0.f, 0.f, 0.f, 0.f};
  float M = -3e38f, S = 0.f;

  v8s kf[4];
#pragma unroll
  for (int f = 0; f < 4; ++f)
    kf[f] = *(const v8s*)&qkb[(size_t)(f * 16 + l15) * 64 + 32 + l4 * 8];
  VMCNT(0);  // kf(0) landed
  SCHEDB;

  // ---- phase 0: QK^T(0), online init, Pl[0], fscL[0], kf(1), stage V(0) ----
  {
    v4f lt[4];
#pragma unroll
    for (int f = 0; f < 4; ++f)
      lt[f] = __builtin_amdgcn_mfma_f32_16x16x32_bf16(
          kf[f], qf, v4f{0.f, 0.f, 0.f, 0.f}, 0, 0, 0);
    float pmax = -3e38f;
#pragma unroll
    for (int f = 0; f < 4; ++f)
#pragma unroll
      for (int r = 0; r < 4; ++r) pmax = fmaxf(pmax, lt[f][r]);
    pmax = fmaxf(pmax, __shfl_xor(pmax, 16));
    pmax = fmaxf(pmax, __shfl_xor(pmax, 32));
    const float Mn = fmaxf(M, pmax);
    const float fsc = exp2f(M - Mn);  // = 0 at t=0
    float sum = 0.f;
#pragma unroll
    for (int f = 0; f < 4; ++f) {
      const float p0 = exp2f(lt[f][0] - Mn);
      const float p1 = exp2f(lt[f][1] - Mn);
      const float p2 = exp2f(lt[f][2] - Mn);
      const float p3 = exp2f(lt[f][3] - Mn);
      sum += (p0 + p1) + (p2 + p3);
      uint2 pw;
      pw.x = cvtpk(p0, p1);
      pw.y = cvtpk(p2, p3);
      *(uint2*)&Pl[0][wid * 16 + l15][f * 16 + l4 * 4] = pw;
    }
    S = S * fsc + sum;
    M = Mn;
    if (l4 == 0) fscL[0][wid * 16 + l15] = fsc;
#pragma unroll
    for (int f = 0; f < 4; ++f)
      kf[f] = *(const v8s*)&qkb[(size_t)(64 + f * 16 + l15) * 64 + 32 + l4 * 8];
    SCHEDB;
#pragma unroll
    for (int g = 0; g < 8; ++g) {
      const int base = cq + g * 8;
      ld_lds16(vb + (size_t)(base + s_row) * N_ + s_j * 8, &Vs[base][0]);
    }
    LGKM0;
    SBAR;
  }

  // ---- phases 1..15 ----
  for (int t = 1; t < 16; ++t) {
    const int pb = (t - 1) & 1, cb = t & 1;
    VMCNT(8);  // kf(t) (4 oldest) landed; V(t-1) stage (8 newest) may fly
    SCHEDB;
    v4f lt[4];
#pragma unroll
    for (int f = 0; f < 4; ++f)
      lt[f] = __builtin_amdgcn_mfma_f32_16x16x32_bf16(
          kf[f], qf, v4f{0.f, 0.f, 0.f, 0.f}, 0, 0, 0);
    // acc rescale to M(t-1) using factors published last phase
    {
      v4f fr[4];
#pragma unroll
      for (int mf = 0; mf < 4; ++mf)
        fr[mf] = *(const v4f*)&fscL[pb][mf * 16 + l4 * 4];
#pragma unroll
      for (int mf = 0; mf < 4; ++mf)
#pragma unroll
        for (int j = 0; j < 4; ++j)
#pragma unroll
          for (int r = 0; r < 4; ++r) acc[mf][j][r] *= fr[mf][r];
    }
    VMCNT(0);  // V(t-1) landed in own quarter
    SCHEDB;
    __builtin_amdgcn_s_setprio(1);
#pragma unroll
    for (int ks = 0; ks < 2; ++ks) {
      v8s pa[4];
#pragma unroll
      for (int mf = 0; mf < 4; ++mf)
        pa[mf] = *(const v8s*)&Pl[pb][mf * 16 + l15][ks * 32 + l4 * 8];
#pragma unroll
      for (int j = 0; j < 4; ++j) {
        const int col = 8 * (((ks * 4) + l4) ^ (l15 & 7));
        const v8s vf = *(const v8s*)&Vs[cq + j * 16 + l15][col];
#pragma unroll
        for (int mf = 0; mf < 4; ++mf)
          acc[mf][j] = __builtin_amdgcn_mfma_f32_16x16x32_bf16(
              pa[mf], vf, acc[mf][j], 0, 0, 0);
      }
    }
    __builtin_amdgcn_s_setprio(0);
    // online M/S update + exp2(t) (overlaps MFMA drain)
    {
      float pmax = -3e38f;
#pragma unroll
      for (int f = 0; f < 4; ++f)
#pragma unroll
        for (int r = 0; r < 4; ++r) pmax = fmaxf(pmax, lt[f][r]);
      pmax = fmaxf(pmax, __shfl_xor(pmax, 16));
      pmax = fmaxf(pmax, __shfl_xor(pmax, 32));
      const float Mn = fmaxf(M, pmax);
      const float fsc = exp2f(M - Mn);
      float sum = 0.f;
#pragma unroll
      for (int f = 0; f < 4; ++f) {
        const float p0 = exp2f(lt[f][0] - Mn);
        const float p1 = exp2f(lt[f][1] - Mn);
        const float p2 = exp2f(lt[f][2] - Mn);
        const float p3 = exp2f(lt[f][3] - Mn);
        sum += (p0 + p1) + (p2 + p3);
        uint2 pw;
        pw.x = cvtpk(p0, p1);
        pw.y = cvtpk(p2, p3);
        *(uint2*)&Pl[cb][wid * 16 + l15][f * 16 + l4 * 4] = pw;
      }
      S = S * fsc + sum;
      M = Mn;
      if (l4 == 0) fscL[cb][wid * 16 + l15] = fsc;
    }
    // kf(t+1) (wrap keeps vmcnt counts uniform)
    {
      const int n1 = ((t + 1) & 15) * 64;
#pragma unroll
      for (int f = 0; f < 4; ++f)
        kf[f] =
            *(const v8s*)&qkb[(size_t)(n1 + f * 16 + l15) * 64 + 32 + l4 * 8];
    }
    SCHEDB;
    // stage V(t) into own quarter (after own PV reads of V(t-1))
    {
      const int n1 = t * 64;
#pragma unroll
      for (int g = 0; g < 8; ++g) {
        const int base = cq + g * 8;
        ld_lds16(vb + (size_t)(base + s_row) * N_ + n1 + s_j * 8, &Vs[base][0]);
      }
    }
    LGKM0;  // P(t)/fsc writes retired -> visible after barrier
    SBAR;
  }

  // ---- epilogue: final rescale + PV(15) ----
  VMCNT(0);
  SCHEDB;
  {
    v4f fr[4];
#pragma unroll
    for (int mf = 0; mf < 4; ++mf)
      fr[mf] = *(const v4f*)&fscL[1][mf * 16 + l4 * 4];
#pragma unroll
    for (int mf = 0; mf < 4; ++mf)
#pragma unroll
      for (int j = 0; j < 4; ++j)
#pragma unroll
        for (int r = 0; r < 4; ++r) acc[mf][j][r] *= fr[mf][r];
  }
  __builtin_amdgcn_s_setprio(1);
#pragma unroll
  for (int ks = 0; ks < 2; ++ks) {
    v8s pa[4];
#pragma unroll
    for (int mf = 0; mf < 4; ++mf)
      pa[mf] = *(const v8s*)&Pl[1][mf * 16 + l15][ks * 32 + l4 * 8];
#pragma unroll
    for (int j = 0; j < 4; ++j) {
      const int col = 8 * (((ks * 4) + l4) ^ (l15 & 7));
      const v8s vf = *(const v8s*)&Vs[cq + j * 16 + l15][col];
#pragma unroll
      for (int mf = 0; mf < 4; ++mf)
        acc[mf][j] = __builtin_amdgcn_mfma_f32_16x16x32_bf16(
            pa[mf], vf, acc[mf][j], 0, 0, 0);
    }
  }
  __builtin_amdgcn_s_setprio(0);

  // S combine across l4 groups (same M per row); publish 1/S
  S += __shfl_xor(S, 16);
  S += __shfl_xor(S, 32);
  if (lane < 16) Sl[wid * 16 + lane] = 1.f / S;
  __syncthreads();  // Sl ready; all PV reads of pool done

  // stage abf[m0..m0+64)[0..256) into AB (coalesced), stride 264
#pragma unroll
  for (int s = 0; s < 8; ++s) {
    const int e = s * 256 + tid;
    const int row = e >> 5, col = (e & 31) * 8;
    const uint4 v =
        *(const uint4*)(abf + ((size_t)b * N_ + m0 + row) * C_ + col);
    *(uint4*)&AB[row * 264 + col] = v;
  }
  float invv[4][4];
#pragma unroll
  for (int mf = 0; mf < 4; ++mf)
#pragma unroll
    for (int r = 0; r < 4; ++r) invv[mf][r] = Sl[mf * 16 + l4 * 4 + r];
  __syncthreads();  // AB ready

  const float gma = gamma_p[0];
#pragma unroll
  for (int mf = 0; mf < 4; ++mf) {
    const int mb = m0 + mf * 16 + l4 * 4;
#pragma unroll
    for (int j = 0; j < 4; ++j) {
      const int c = cq + j * 16 + l15;
      float4 y;
      float* yp = (float*)&y;
#pragma unroll
      for (int r = 0; r < 4; ++r) {
        const float av = bf2f(AB[(mf * 16 + l4 * 4 + r) * 264 + c]);
        yp[r] = fmaxf(gma * acc[mf][j][r] * invv[mf][r] + av, 0.f);
      }
      *(float4*)&out[((size_t)b * C_ + c) * N_ + mb] = y;
    }
  }
}

// ---------------------------------------------------------------------------
extern "C" void kernel_launch(void* const* d_in, const int* in_sizes, int n_in,
                              void* d_out, int out_size, void* d_ws,
                              size_t ws_size, hipStream_t stream) {
  const float* x = (const float*)d_in[0];
  const float* dw1 = (const float*)d_in[1];
  const float* pw1 = (const float*)d_in[2];
  const float* bn1g = (const float*)d_in[3];
  const float* bn1b = (const float*)d_in[4];
  const float* bn1m = (const float*)d_in[5];
  const float* bn1v = (const float*)d_in[6];
  const float* dw2 = (const float*)d_in[7];
  const float* pw2 = (const float*)d_in[8];
  const float* bn2g = (const float*)d_in[9];
  const float* bn2b = (const float*)d_in[10];
  const float* bn2m = (const float*)d_in[11];
  const float* bn2v = (const float*)d_in[12];
  const float* wq = (const float*)d_in[13];
  const float* bq = (const float*)d_in[14];
  const float* wk = (const float*)d_in[15];
  const float* bk = (const float*)d_in[16];
  const float* wv = (const float*)d_in[17];
  const float* bv = (const float*)d_in[18];
  const float* gamma = (const float*)d_in[19];
  float* out = (float*)d_out;

  char* ws = (char*)d_ws;
  size_t off = 0;
  auto alloc = [&](size_t bytes) {
    void* p = ws + off;
    off += (bytes + 255) & ~(size_t)255;
    return p;
  };
  const size_t NE = (size_t)B_ * N_ * C_;  // 16.78M elements

  u16* bufA = (u16*)alloc(NE * 2);  // xt, later vchw
  u16* bufB = (u16*)alloc(NE * 2);  // t1, later t2
  u16* bufC = (u16*)alloc(NE * 2);  // y1, later qk
  u16* abf = (u16*)alloc(NE * 2);
  float* scale1 = (float*)alloc(256 * 4);
  float* shift1 = (float*)alloc(256 * 4);
  float* scale2 = (float*)alloc(256 * 4);
  float* shift2 = (float*)alloc(256 * 4);
  float* dwT1 = (float*)alloc(2304 * 4);
  float* dwT2 = (float*)alloc(2304 * 4);
  u16* pw1b = (u16*)alloc(65536 * 2);
  u16* pw2b = (u16*)alloc(65536 * 2);
  u16* wcatb = (u16*)alloc(81920 * 2);
  float* bcat = (float*)alloc(384 * 4);

  u16* xt = bufA;
  u16* t1 = bufB;
  u16* y1 = bufC;
  u16* t2 = bufB;
  u16* qkbuf = bufC;
  u16* vchw = bufA;

  prep<<<64, 256, 0, stream>>>(bn1g, bn1b, bn1m, bn1v, bn2g, bn2b, bn2m, bn2v,
                               wq, bq, wk, bk, wv, bv, pw1, pw2, dw1, dw2,
                               scale1, shift1, scale2, shift2, dwT1, dwT2,
                               pw1b, pw2b, wcatb, bcat);
  transpose_x<<<dim3(16, 4, B_), 256, 0, stream>>>(x, xt);
  dw_nhwc<<<dim3(128, B_), 256, 0, stream>>>(xt, dwT1, t1);
  gemm<0><<<dim3(8, 2, B_), 256, 0, stream>>>(t1, pw1b, scale1, shift1,
                                              nullptr, y1, nullptr);
  dw_nhwc<<<dim3(128, B_), 256, 0, stream>>>(y1, dwT2, t2);
  gemm<1><<<dim3(8, 2, B_), 256, 0, stream>>>(t2, pw2b, scale2, shift2, xt,
                                              abf, nullptr);
  gemm<2><<<dim3(8, 3, B_), 256, 0, stream>>>(abf, wcatb, nullptr, bcat,
                                              nullptr, qkbuf, vchw);
  flash<<<dim3(64, 16), 256, 0, stream>>>(qkbuf, vchw, abf, gamma, out);
}